// Round 14
// baseline (495.280 us; speedup 1.0000x reference)
//
#include <hip/hip_runtime.h>
#include <cstdint>
#include <cstddef>

#define NEG_SLOPE 0.2f
#define BN_EPS 1e-5f

typedef __bf16 bf16x8 __attribute__((ext_vector_type(8)));
typedef float  f32x4  __attribute__((ext_vector_type(4)));

// single-instruction byte->float (v_cvt_f32_ubyteN)
__device__ __forceinline__ float ub0(unsigned u) { return (float)(u & 0xffu); }
__device__ __forceinline__ float ub1(unsigned u) { return (float)((u >> 8) & 0xffu); }
__device__ __forceinline__ float ub2(unsigned u) { return (float)((u >> 16) & 0xffu); }
__device__ __forceinline__ float ub3(unsigned u) { return (float)((u >> 24) & 0xffu); }

// ---------- prep: x fp32 [N][K] -> bf16 [N][Kpad] zero-padded ----------
__global__ void conv_pad_kernel(const float* __restrict__ x, __bf16* __restrict__ xb,
                                int N, int K, int Kpad) {
    int i = blockIdx.x * blockDim.x + threadIdx.x;
    int total = N * Kpad;
    for (; i < total; i += gridDim.x * blockDim.x) {
        int n = i / Kpad, k = i - n * Kpad;
        xb[i] = (k < K) ? (__bf16)x[(size_t)n * K + k] : (__bf16)0.f;
    }
}

// ---------- prep: weight transposes + BN coefficient fold, one launch ----------
__global__ void prep_all_kernel(
    const float* __restrict__ W1, const float* __restrict__ W2,
    const float* __restrict__ W3, const float* __restrict__ W4,
    const float* __restrict__ PW1,
    __bf16* __restrict__ wt1, __bf16* __restrict__ wt2,
    __bf16* __restrict__ wt3, __bf16* __restrict__ wt4,
    __bf16* __restrict__ pw1t,
    const float* b1, const float* g1, const float* e1, const float* m1, const float* v1,
    const float* b2, const float* g2, const float* e2, const float* m2, const float* v2,
    const float* b3, const float* g3, const float* e3, const float* m3, const float* v3,
    const float* b4, const float* g4, const float* e4, const float* m4, const float* v4,
    float* __restrict__ bnS, float* __restrict__ bnT,   // [4][256]
    int IN) {
    int b = blockIdx.x;
    if (b >= 928) {
        int l = b - 928;
        int Dl = (l == 3) ? 128 : 256;
        int t = threadIdx.x;
        if (t < Dl) {
            const float* bias; const float* ga; const float* be;
            const float* mu;   const float* va;
            if (l == 0)      { bias = b1; ga = g1; be = e1; mu = m1; va = v1; }
            else if (l == 1) { bias = b2; ga = g2; be = e2; mu = m2; va = v2; }
            else if (l == 2) { bias = b3; ga = g3; be = e3; mu = m3; va = v3; }
            else             { bias = b4; ga = g4; be = e4; mu = m4; va = v4; }
            float S = ga[t] * rsqrtf(va[t] + BN_EPS);
            bnS[l * 256 + t] = S;
            bnT[l * 256 + t] = (bias[t] - mu[t]) * S + be[t];
        }
        return;
    }
    const float* W; __bf16* WT; int K, D, Kpad, col;
    if (b < 256)      { W = W1;  WT = wt1;  K = IN;  D = 256; Kpad = 64;  col = b; }
    else if (b < 512) { W = W2;  WT = wt2;  K = 256; D = 256; Kpad = 256; col = b - 256; }
    else if (b < 768) { W = W3;  WT = wt3;  K = 256; D = 256; Kpad = 256; col = b - 512; }
    else if (b < 896) { W = W4;  WT = wt4;  K = 256; D = 128; Kpad = 256; col = b - 768; }
    else              { W = PW1; WT = pw1t; K = 128; D = 32;  Kpad = 128; col = b - 896; }
    for (int k = threadIdx.x; k < Kpad; k += blockDim.x)
        WT[(size_t)col * Kpad + k] = (k < K) ? (__bf16)W[(size_t)k * D + col] : (__bf16)0.f;
}

// ================= LDS-free MFMA GEMM (32x64 per wave) + fused alpha + u8 H ====
// KT = compile-time K (full unroll -> compiler pipelines the loads).
// Quant scale per (row, 64-col block): hscale[row*NSB + sb].
// DCOLS==256: block = 32 rows x 256 cols, wave w = head w, NO LDS / NO barriers.
// DCOLS==128: block = 64 rows x 128 cols, wave = (roww, colhalf); LDS only for alpha.
template<int DCOLS, int KT, bool HAS_A2>
__global__ __launch_bounds__(256) void gemm_fused(
    const __bf16* __restrict__ A, const __bf16* __restrict__ A2,
    const __bf16* __restrict__ WT,
    const float* __restrict__ asv, const float* __restrict__ adv,
    uint8_t* __restrict__ H8, float* __restrict__ hscale,
    float* __restrict__ alpha_s, float* __restrict__ alpha_d,
    int M) {
    constexpr int NSB = DCOLS / 64;
    constexpr int RB  = (DCOLS == 256) ? 32 : 64;
    const int w    = threadIdx.x >> 6;
    const int lane = threadIdx.x & 63;
    const int l16  = lane & 15, hi4 = lane >> 4;
    const int rbase = (DCOLS == 256) ? 0 : (w >> 1) * 32;
    const int ct    = (DCOLS == 256) ? w : (w & 1);     // column-block (= head for 256)
    const int col0w = ct * 64;
    const int n0 = blockIdx.x * RB;
    const int lk = hi4 * 8;

    f32x4 acc[2][4] = {};
    int arow[2];
    #pragma unroll
    for (int i = 0; i < 2; ++i) {
        int r = n0 + rbase + i * 16 + l16;
        arow[i] = (r < M) ? r : (M - 1);
    }

    #pragma unroll
    for (int k0 = 0; k0 < KT; k0 += 32) {
        bf16x8 af[2], bfr[4];
        #pragma unroll
        for (int i = 0; i < 2; ++i) {
            bf16x8 v = *(const bf16x8*)&A[(size_t)arow[i] * KT + k0 + lk];
            if (HAS_A2) {
                bf16x8 v2 = *(const bf16x8*)&A2[(size_t)arow[i] * KT + k0 + lk];
                #pragma unroll
                for (int j = 0; j < 8; ++j) v[j] = (__bf16)((float)v[j] + (float)v2[j]);
            }
            af[i] = v;
        }
        #pragma unroll
        for (int j = 0; j < 4; ++j)
            bfr[j] = *(const bf16x8*)&WT[(size_t)(col0w + j * 16 + l16) * KT + k0 + lk];
        #pragma unroll
        for (int i = 0; i < 2; ++i)
            #pragma unroll
            for (int j = 0; j < 4; ++j)
                acc[i][j] = __builtin_amdgcn_mfma_f32_16x16x32_bf16(
                    af[i], bfr[j], acc[i][j], 0, 0, 0);
    }

    // ---- fused alpha (partial dot over this wave's 64 cols) ----
    float asc[4], adc[4];
    #pragma unroll
    for (int j = 0; j < 4; ++j) {
        int c = col0w + j * 16 + l16;
        asc[j] = asv[c]; adc[j] = adv[c];
    }
    __shared__ float as_l[(DCOLS == 128) ? 64 : 1][2], ad_l[(DCOLS == 128) ? 64 : 1][2];
    #pragma unroll
    for (int i = 0; i < 2; ++i)
        #pragma unroll
        for (int q = 0; q < 4; ++q) {
            float ps = 0.f, pd = 0.f;
            #pragma unroll
            for (int j = 0; j < 4; ++j) {
                float v = acc[i][j][q];
                ps = fmaf(v, asc[j], ps);
                pd = fmaf(v, adc[j], pd);
            }
            #pragma unroll
            for (int o = 1; o < 16; o <<= 1) {
                ps += __shfl_xor(ps, o, 64);
                pd += __shfl_xor(pd, o, 64);
            }
            int rl = rbase + i * 16 + hi4 * 4 + q;
            if constexpr (DCOLS == 256) {
                int row = n0 + rl;
                if (l16 == 0 && row < M) {
                    alpha_s[row * 4 + w] = ps;
                    alpha_d[row * 4 + w] = pd;
                }
            } else {
                if (l16 == 0) { as_l[rl][ct] = ps; ad_l[rl][ct] = pd; }
            }
        }
    if constexpr (DCOLS == 128) {
        __syncthreads();
        int t = threadIdx.x;
        if (t < 64) {
            int row = n0 + t;
            if (row < M) {
                alpha_s[row] = as_l[t][0] + as_l[t][1];
                alpha_d[row] = ad_l[t][0] + ad_l[t][1];
            }
        }
    }

    // ---- per-wave (row, 64-col block) max|acc| -> quantize (excess-128) ----
    #pragma unroll
    for (int i = 0; i < 2; ++i)
        #pragma unroll
        for (int q = 0; q < 4; ++q) {
            float m = fabsf(acc[i][0][q]);
            #pragma unroll
            for (int j = 1; j < 4; ++j) m = fmaxf(m, fabsf(acc[i][j][q]));
            #pragma unroll
            for (int o = 1; o < 16; o <<= 1) m = fmaxf(m, __shfl_xor(m, o, 64));
            float qinv = (m > 1e-30f) ? 127.f / m : 0.f;
            int row = n0 + rbase + i * 16 + hi4 * 4 + q;
            if (row < M) {
                if (l16 == 0) hscale[row * NSB + ct] = m * (1.f / 127.f);
                #pragma unroll
                for (int j = 0; j < 4; ++j)
                    H8[(size_t)row * DCOLS + col0w + j * 16 + l16] =
                        (uint8_t)((int)rintf(acc[i][j][q] * qinv) + 128);
            }
        }
}

// ================= CSR build (once per call) =================
__global__ void deg_count_kernel(const int* __restrict__ ei, int* __restrict__ deg,
                                 int E, int Etot) {
    int e = blockIdx.x * blockDim.x + threadIdx.x;
    if (e >= Etot) return;
    int d = (e < E) ? ei[E + e] : e - E;
    atomicAdd(&deg[d], 1);
}

#define SCB 4096
__global__ __launch_bounds__(256) void scan1_kernel(const int* __restrict__ deg,
                                                    int* __restrict__ bsum, int N) {
    __shared__ int ts[256];
    const int t = threadIdx.x;
    const int base = blockIdx.x * SCB + t * 16;
    int s = 0;
    #pragma unroll
    for (int i = 0; i < 16; ++i) {
        int idx = base + i;
        if (idx < N) s += deg[idx];
    }
    ts[t] = s;
    __syncthreads();
    for (int off = 128; off > 0; off >>= 1) {
        if (t < off) ts[t] += ts[t + off];
        __syncthreads();
    }
    if (t == 0) bsum[blockIdx.x] = ts[0];
}

__global__ __launch_bounds__(256) void scan2_kernel(const int* __restrict__ bsum,
                                                    int* __restrict__ bpref, int B,
                                                    int* __restrict__ rowptrN) {
    __shared__ int sm[256];
    const int t = threadIdx.x;
    int v = (t < B) ? bsum[t] : 0;
    sm[t] = v;
    __syncthreads();
    for (int off = 1; off < 256; off <<= 1) {
        int u = (t >= off) ? sm[t - off] : 0;
        __syncthreads();
        sm[t] += u;
        __syncthreads();
    }
    if (t < B) bpref[t] = sm[t] - v;
    if (t == 255) *rowptrN = sm[255];
}

__global__ __launch_bounds__(256) void scan3_kernel(const int* __restrict__ deg,
                                                    const int* __restrict__ bpref,
                                                    int* __restrict__ rowptr,
                                                    int* __restrict__ cursor, int N) {
    __shared__ int ts[256];
    const int t = threadIdx.x;
    const int base = blockIdx.x * SCB + t * 16;
    int d[16];
    int s = 0;
    #pragma unroll
    for (int i = 0; i < 16; ++i) {
        int idx = base + i;
        d[i] = (idx < N) ? deg[idx] : 0;
        s += d[i];
    }
    ts[t] = s;
    __syncthreads();
    for (int off = 1; off < 256; off <<= 1) {
        int u = (t >= off) ? ts[t - off] : 0;
        __syncthreads();
        ts[t] += u;
        __syncthreads();
    }
    int run = bpref[blockIdx.x] + ts[t] - s;
    #pragma unroll
    for (int i = 0; i < 16; ++i) {
        int idx = base + i;
        if (idx < N) { rowptr[idx] = run; cursor[idx] = run; run += d[i]; }
    }
}

__global__ void scatter_kernel(const int* __restrict__ ei, int* __restrict__ cursor,
                               int* __restrict__ csrc, int E, int Etot) {
    int e = blockIdx.x * blockDim.x + threadIdx.x;
    if (e >= Etot) return;
    int s, d;
    if (e < E) { s = ei[e]; d = ei[E + e]; } else { s = d = e - E; }
    int pos = atomicAdd(&cursor[d], 1);
    csrc[pos] = s;
}

__global__ void gstart_kernel(const int* __restrict__ batch, int* __restrict__ gstart,
                              int N, int G) {
    int n = blockIdx.x * blockDim.x + threadIdx.x;
    if (n >= N) return;
    int b = batch[n];
    if (n == 0) { for (int g = 0; g <= b; ++g) gstart[g] = 0; }
    else {
        int bp = batch[n - 1];
        for (int g = bp + 1; g <= b; ++g) gstart[g] = n;
    }
    if (n == N - 1) { for (int g = b + 1; g <= G; ++g) gstart[g] = N; }
}

// ============ GAT edge phase: TWO nodes per wave, per-block-scale u8 gather ====
// hscale layout [N][NSB], NSB = D/64. Scale folded per scale-block into pal.
template<int HEADS, int C>
__global__ __launch_bounds__(256) void gat_agg(
    const int* __restrict__ rowptr, const int* __restrict__ csrc,
    const uint8_t* __restrict__ hf, const float* __restrict__ hscale,
    const float* __restrict__ asrc, const float* __restrict__ adst,
    const float* __restrict__ bnS, const float* __restrict__ bnT,
    __bf16* __restrict__ out, int N) {
    constexpr int D   = HEADS * C;
    constexpr int NSB = D / 64;       // scale blocks per row (4 or 2)
    constexpr int LPE = D / 8;        // lanes covering one row (32 or 16)
    constexpr int EPH = 32 / LPE;     // edges per half-step (1 or 2)

    const int wid  = threadIdx.x >> 6;
    const int lane = threadIdx.x & 63;
    const int half = lane >> 5;
    const int sl   = lane & 31;

    __shared__ int   soff[4][2][32];
    __shared__ float pal[4][2][32][NSB];

    const int npairs = (N + 1) >> 1;

    for (int pair = blockIdx.x * 4 + wid; pair < npairs; pair += gridDim.x * 4) {
        const int node = pair * 2 + half;
        const bool valid = node < N;
        const int beg = valid ? rowptr[node] : 0;
        const int end = valid ? rowptr[node + 1] : 0;
        const int deg = end - beg;

        const int grp = (EPH == 1) ? 0 : (sl >> 4);
        const int c0  = (EPH == 1) ? sl * 8 : (sl & 15) * 8;
        const int sb  = c0 >> 6;          // scale-block of my columns
        const uint8_t* hb = hf + c0;

        float ad[HEADS];
        #pragma unroll
        for (int h = 0; h < HEADS; ++h) ad[h] = valid ? adst[node * HEADS + h] : 0.f;

        float acc8[8] = {};
        float psum = 0.f;

        auto fmau8 = [&](uint2 v, float q) {
            acc8[0] = fmaf(ub0(v.x), q, acc8[0]);
            acc8[1] = fmaf(ub1(v.x), q, acc8[1]);
            acc8[2] = fmaf(ub2(v.x), q, acc8[2]);
            acc8[3] = fmaf(ub3(v.x), q, acc8[3]);
            acc8[4] = fmaf(ub0(v.y), q, acc8[4]);
            acc8[5] = fmaf(ub1(v.y), q, acc8[5]);
            acc8[6] = fmaf(ub2(v.y), q, acc8[6]);
            acc8[7] = fmaf(ub3(v.y), q, acc8[7]);
        };

        auto agg_chunk = [&](int cnt) {
            int e = 0;
            for (; e + 4 * EPH <= cnt; e += 4 * EPH) {
                int o0 = soff[wid][half][e + 0 * EPH + grp];
                int o1 = soff[wid][half][e + 1 * EPH + grp];
                int o2 = soff[wid][half][e + 2 * EPH + grp];
                int o3 = soff[wid][half][e + 3 * EPH + grp];
                float q0 = pal[wid][half][e + 0 * EPH + grp][sb];
                float q1 = pal[wid][half][e + 1 * EPH + grp][sb];
                float q2 = pal[wid][half][e + 2 * EPH + grp][sb];
                float q3 = pal[wid][half][e + 3 * EPH + grp][sb];
                uint2 v0 = *(const uint2*)(hb + o0);
                uint2 v1 = *(const uint2*)(hb + o1);
                uint2 v2 = *(const uint2*)(hb + o2);
                uint2 v3 = *(const uint2*)(hb + o3);
                psum += (q0 + q1) + (q2 + q3);
                fmau8(v0, q0); fmau8(v1, q1); fmau8(v2, q2); fmau8(v3, q3);
            }
            for (; e + EPH <= cnt; e += EPH) {
                int o0 = soff[wid][half][e + grp];
                float q0 = pal[wid][half][e + grp][sb];
                uint2 v0 = *(const uint2*)(hb + o0);
                psum += q0;
                fmau8(v0, q0);
            }
            if (EPH == 2 && e < cnt) {
                int r = cnt - e;
                int idx = (grp < r) ? e + grp : e;
                int o0 = soff[wid][half][idx];
                float q0 = (grp < r) ? pal[wid][half][idx][sb] : 0.f;
                uint2 v0 = *(const uint2*)(hb + o0);
                psum += q0;
                fmau8(v0, q0);
            }
        };

        if (deg <= 32) {
            // ---- fast path: slot sl = edge, width-32 butterflies ----
            const bool act = sl < deg;
            int msrc = act ? csrc[beg + sl] : 0;
            float lv[HEADS];
            if constexpr (HEADS == 4) {
                float4 a4 = ((const float4*)asrc)[msrc];
                lv[0] = a4.x; lv[1] = a4.y; lv[2] = a4.z; lv[3] = a4.w;
            } else {
                lv[0] = asrc[msrc];
            }
            float pe_[HEADS];
            #pragma unroll
            for (int h = 0; h < HEADS; ++h) {
                float v;
                if (act) { v = lv[h] + ad[h]; v = v > 0.f ? v : NEG_SLOPE * v; }
                else v = -INFINITY;
                float mx = v;
                #pragma unroll
                for (int o = 1; o < 32; o <<= 1) mx = fmaxf(mx, __shfl_xor(mx, o, 64));
                float pe = act ? __expf(v - mx) : 0.f;
                float ps = pe;
                #pragma unroll
                for (int o = 1; o < 32; o <<= 1) ps += __shfl_xor(ps, o, 64);
                pe_[h] = pe * (1.f / (ps + 1e-16f));
            }
            soff[wid][half][sl] = msrc * D;
            if constexpr (HEADS == 4) {
                float4 hs = act ? ((const float4*)hscale)[msrc]
                                : make_float4(0.f, 0.f, 0.f, 0.f);
                *(float4*)&pal[wid][half][sl][0] =
                    make_float4(pe_[0] * hs.x, pe_[1] * hs.y, pe_[2] * hs.z, pe_[3] * hs.w);
            } else {
                float2 hs = act ? ((const float2*)hscale)[msrc] : make_float2(0.f, 0.f);
                *(float2*)&pal[wid][half][sl][0] = make_float2(pe_[0] * hs.x, pe_[0] * hs.y);
            }
            asm volatile("s_waitcnt lgkmcnt(0)" ::: "memory");
            agg_chunk(deg);
        } else {
            // ---- general path (deg > 32; rare), per-half strided two-pass ----
            float mx[HEADS], sm[HEADS], inv[HEADS];
            #pragma unroll
            for (int h = 0; h < HEADS; ++h) mx[h] = -INFINITY;
            for (int j = beg + sl; j < end; j += 32) {
                int s = csrc[j];
                #pragma unroll
                for (int h = 0; h < HEADS; ++h) {
                    float v = asrc[s * HEADS + h] + ad[h];
                    v = v > 0.f ? v : NEG_SLOPE * v;
                    mx[h] = fmaxf(mx[h], v);
                }
            }
            #pragma unroll
            for (int h = 0; h < HEADS; ++h) {
                #pragma unroll
                for (int o = 1; o < 32; o <<= 1) mx[h] = fmaxf(mx[h], __shfl_xor(mx[h], o, 64));
                sm[h] = 0.f;
            }
            for (int j = beg + sl; j < end; j += 32) {
                int s = csrc[j];
                #pragma unroll
                for (int h = 0; h < HEADS; ++h) {
                    float v = asrc[s * HEADS + h] + ad[h];
                    v = v > 0.f ? v : NEG_SLOPE * v;
                    sm[h] += __expf(v - mx[h]);
                }
            }
            #pragma unroll
            for (int h = 0; h < HEADS; ++h) {
                #pragma unroll
                for (int o = 1; o < 32; o <<= 1) sm[h] += __shfl_xor(sm[h], o, 64);
                inv[h] = 1.f / (sm[h] + 1e-16f);
            }
            for (int base2 = beg; base2 < end; base2 += 32) {
                int ne = min(32, end - base2);
                bool act2 = sl < ne;
                int msrc = csrc[base2 + (act2 ? sl : 0)];
                soff[wid][half][sl] = msrc * D;
                if constexpr (HEADS == 4) {
                    float4 hs = act2 ? ((const float4*)hscale)[msrc]
                                     : make_float4(0.f, 0.f, 0.f, 0.f);
                    float hsv[4] = {hs.x, hs.y, hs.z, hs.w};
                    #pragma unroll
                    for (int h = 0; h < 4; ++h) {
                        float pv = 0.f;
                        if (act2) {
                            float v = asrc[msrc * 4 + h] + ad[h];
                            v = v > 0.f ? v : NEG_SLOPE * v;
                            pv = __expf(v - mx[h]) * inv[h];
                        }
                        pal[wid][half][sl][h] = pv * hsv[h];
                    }
                } else {
                    float2 hs = act2 ? ((const float2*)hscale)[msrc] : make_float2(0.f, 0.f);
                    float pv = 0.f;
                    if (act2) {
                        float v = asrc[msrc] + ad[0];
                        v = v > 0.f ? v : NEG_SLOPE * v;
                        pv = __expf(v - mx[0]) * inv[0];
                    }
                    pal[wid][half][sl][0] = pv * hs.x;
                    pal[wid][half][sl][1] = pv * hs.y;
                }
                asm volatile("s_waitcnt lgkmcnt(0)" ::: "memory");
                agg_chunk(ne);
                asm volatile("s_waitcnt lgkmcnt(0)" ::: "memory");
            }
        }

        // ---- merge (D=128 only: lanes sl, sl^16 share cols) ----
        if constexpr (EPH == 2) {
            #pragma unroll
            for (int i = 0; i < 8; ++i)
                acc8[i] += __shfl_xor(acc8[i], 16, 64);
            psum += __shfl_xor(psum, 16, 64);
        }

        // ---- epilogue: excess-128 fix + folded BN + ReLU -> bf16 ----
        if (valid && (EPH == 1 || sl < 16)) {
            float4 Sa = *(const float4*)&bnS[c0];
            float4 Sb = *(const float4*)&bnS[c0 + 4];
            float4 Ta = *(const float4*)&bnT[c0];
            float4 Tb = *(const float4*)&bnT[c0 + 4];
            float S8[8] = {Sa.x, Sa.y, Sa.z, Sa.w, Sb.x, Sb.y, Sb.z, Sb.w};
            float T8[8] = {Ta.x, Ta.y, Ta.z, Ta.w, Tb.x, Tb.y, Tb.z, Tb.w};
            bf16x8 ov;
            #pragma unroll
            for (int i = 0; i < 8; ++i) {
                float v = fmaf(acc8[i] - 128.f * psum, S8[i], T8[i]);
                ov[i] = (__bf16)fmaxf(v, 0.f);
            }
            *(bf16x8*)&out[(size_t)node * D + c0] = ov;
        }
    }
}

// ---------- gate MLP via MFMA ----------
__global__ __launch_bounds__(256) void gate_gemm_kernel(
    const __bf16* __restrict__ x4, const __bf16* __restrict__ pw1t,
    const float* __restrict__ pb1, const float* __restrict__ pw2,
    const float* __restrict__ pb2, float* __restrict__ gate, int N) {
    const int w    = threadIdx.x >> 6;
    const int lane = threadIdx.x & 63;
    const int l16  = lane & 15, hi4 = lane >> 4;
    const int n0 = (blockIdx.x * 4 + w) * 16;
    if (n0 >= N) return;
    const int arow = min(n0 + l16, N - 1);
    f32x4 acc[2] = {};
    #pragma unroll
    for (int k0 = 0; k0 < 128; k0 += 32) {
        bf16x8 af = *(const bf16x8*)&x4[(size_t)arow * 128 + k0 + hi4 * 8];
        bf16x8 b0 = *(const bf16x8*)&pw1t[(size_t)l16 * 128 + k0 + hi4 * 8];
        bf16x8 b1 = *(const bf16x8*)&pw1t[(size_t)(16 + l16) * 128 + k0 + hi4 * 8];
        acc[0] = __builtin_amdgcn_mfma_f32_16x16x32_bf16(af, b0, acc[0], 0, 0, 0);
        acc[1] = __builtin_amdgcn_mfma_f32_16x16x32_bf16(af, b1, acc[1], 0, 0, 0);
    }
    float pb1a = pb1[l16], pb1b = pb1[16 + l16];
    float w2a = pw2[l16], w2b = pw2[16 + l16];
    #pragma unroll
    for (int q = 0; q < 4; ++q) {
        float g = fmaxf(acc[0][q] + pb1a, 0.f) * w2a +
                  fmaxf(acc[1][q] + pb1b, 0.f) * w2b;
        #pragma unroll
        for (int o = 1; o < 16; o <<= 1) g += __shfl_xor(g, o, 64);
        int row = n0 + hi4 * 4 + q;
        if (l16 == 0 && row < N) gate[row] = g + pb2[0];
    }
}

// ---------- block-per-graph pooling ----------
__global__ __launch_bounds__(128) void pool_kernel(
    const __bf16* __restrict__ x4, const float* __restrict__ gate,
    const int* __restrict__ gstart, float* __restrict__ out) {
    const int g = blockIdx.x;
    const int t = threadIdx.x;
    const int beg = gstart[g], end = gstart[g + 1];
    __shared__ float red[128];
    __shared__ float wbuf[128];
    float m = -INFINITY;
    for (int n = beg + t; n < end; n += 128) m = fmaxf(m, gate[n]);
    red[t] = m; __syncthreads();
    for (int off = 64; off > 0; off >>= 1) {
        if (t < off) red[t] = fmaxf(red[t], red[t + off]);
        __syncthreads();
    }
    m = red[0]; __syncthreads();
    float s = 0.f;
    for (int n = beg + t; n < end; n += 128) s += expf(gate[n] - m);
    red[t] = s; __syncthreads();
    for (int off = 64; off > 0; off >>= 1) {
        if (t < off) red[t] += red[t + off];
        __syncthreads();
    }
    const float inv = 1.f / (red[0] + 1e-16f);
    __syncthreads();
    float acc = 0.f;
    for (int base = beg; base < end; base += 128) {
        int ne = min(128, end - base);
        if (t < ne) wbuf[t] = expf(gate[base + t] - m) * inv;
        __syncthreads();
        for (int i = 0; i < ne; ++i)
            acc = fmaf(wbuf[i], (float)x4[(size_t)(base + i) * 128 + t], acc);
        __syncthreads();
    }
    out[(size_t)g * 160 + t] = acc;
}

// ---------- global-feature MLP ----------
__global__ void gfeat_kernel(const float* __restrict__ gfeat,
                             const float* __restrict__ gw, const float* __restrict__ gb,
                             float* __restrict__ out) {
    const int g = blockIdx.x;
    const int k = threadIdx.x;
    if (k < 32) {
        float t = gb[k];
        #pragma unroll
        for (int j = 0; j < 7; ++j) t = fmaf(gfeat[g * 7 + j], gw[j * 32 + k], t);
        out[(size_t)g * 160 + 128 + k] = fmaxf(t, 0.f);
    }
}

// ==========================================================================
extern "C" void kernel_launch(void* const* d_in, const int* in_sizes, int n_in,
                              void* d_out, int out_size, void* d_ws, size_t ws_size,
                              hipStream_t stream) {
    const float* x      = (const float*)d_in[0];
    const int*   ei     = (const int*)  d_in[1];
    const int*   batch  = (const int*)  d_in[2];
    const float* gfeat  = (const float*)d_in[3];

    const int N    = in_sizes[2];
    const int E    = in_sizes[1] / 2;
    const int G    = in_sizes[3] / 7;
    const int IN   = in_sizes[0] / N;
    const int Etot = E + N;

    const float* W[4];  const float* avs[4]; const float* avd[4]; const float* bi[4];
    const float* ga[4]; const float* be[4];  const float* mu[4];  const float* va[4];
    for (int l = 0; l < 4; ++l) {
        int o = 4 + 8 * l;
        W[l]   = (const float*)d_in[o + 0];
        avs[l] = (const float*)d_in[o + 1];
        avd[l] = (const float*)d_in[o + 2];
        bi[l]  = (const float*)d_in[o + 3];
        ga[l]  = (const float*)d_in[o + 4];
        be[l]  = (const float*)d_in[o + 5];
        mu[l]  = (const float*)d_in[o + 6];
        va[l]  = (const float*)d_in[o + 7];
    }
    const float* pw1 = (const float*)d_in[36];
    const float* pb1 = (const float*)d_in[37];
    const float* pw2 = (const float*)d_in[38];
    const float* pb2 = (const float*)d_in[39];
    const float* gw  = (const float*)d_in[40];
    const float* gb  = (const float*)d_in[41];

    float* out = (float*)d_out;

    float* ws = (float*)d_ws;
    __bf16* xb = (__bf16*)ws; ws += (size_t)N * 32;
    uint8_t* h8 = (uint8_t*)ws; ws += (size_t)N * 64;
    float* hsc = ws;  ws += (size_t)N * 4;      // [N][NSB<=4]
    __bf16* x1 = (__bf16*)ws; ws += (size_t)N * 128;
    __bf16* x2 = (__bf16*)ws; ws += (size_t)N * 128;
    __bf16* x3 = (__bf16*)ws; ws += (size_t)N * 128;
    __bf16* wt1 = (__bf16*)ws; ws += 256 * 64 / 2;
    __bf16* wt2 = (__bf16*)ws; ws += 256 * 256 / 2;
    __bf16* wt3 = (__bf16*)ws; ws += 256 * 256 / 2;
    __bf16* wt4 = (__bf16*)ws; ws += 128 * 256 / 2;
    __bf16* pw1t = (__bf16*)ws; ws += 32 * 128 / 2;
    float* bnS = ws; ws += 4 * 256;
    float* bnT = ws; ws += 4 * 256;
    float* asrc = ws;  ws += (size_t)N * 4;
    float* adst = ws;  ws += (size_t)N * 4;
    float* gate = ws;  ws += N;
    int* deg    = (int*)ws; ws += N;
    int* cursor = (int*)ws; ws += N;
    int* rowptr = (int*)ws; ws += (N + 1);
    int* csrc   = (int*)ws; ws += Etot;
    int* gstart = (int*)ws; ws += (G + 1);
    int* bsum   = (int*)ws; ws += 256;
    int* bpref  = (int*)ws; ws += 256;
    __bf16* x4 = x1;

    const int SB = (N + SCB - 1) / SCB;

    hipLaunchKernelGGL(conv_pad_kernel, dim3(512), dim3(256), 0, stream, x, xb, N, IN, 64);
    hipLaunchKernelGGL(prep_all_kernel, dim3(932), dim3(256), 0, stream,
                       W[0], W[1], W[2], W[3], pw1, wt1, wt2, wt3, wt4, pw1t,
                       bi[0], ga[0], be[0], mu[0], va[0],
                       bi[1], ga[1], be[1], mu[1], va[1],
                       bi[2], ga[2], be[2], mu[2], va[2],
                       bi[3], ga[3], be[3], mu[3], va[3],
                       bnS, bnT, IN);

    hipMemsetAsync(deg, 0, (size_t)N * 4, stream);
    hipLaunchKernelGGL(deg_count_kernel, dim3((Etot + 255) / 256), dim3(256), 0, stream,
                       ei, deg, E, Etot);
    hipLaunchKernelGGL(scan1_kernel, dim3(SB), dim3(256), 0, stream, deg, bsum, N);
    hipLaunchKernelGGL(scan2_kernel, dim3(1), dim3(256), 0, stream, bsum, bpref, SB,
                       &rowptr[N]);
    hipLaunchKernelGGL(scan3_kernel, dim3(SB), dim3(256), 0, stream, deg, bpref,
                       rowptr, cursor, N);
    hipLaunchKernelGGL(scatter_kernel, dim3((Etot + 255) / 256), dim3(256), 0, stream,
                       ei, cursor, csrc, E, Etot);
    hipLaunchKernelGGL(gstart_kernel, dim3((N + 255) / 256), dim3(256), 0, stream,
                       batch, gstart, N, G);

    const int grid32  = (N + 31) / 32;    // 32-row blocks (layers 1-3)
    const int grid64  = (N + 63) / 64;    // 64-row blocks (layer 4)
    const int gatgrid = 2048;

    hipLaunchKernelGGL((gemm_fused<256, 64, false>), dim3(grid32), dim3(256), 0, stream,
                       xb, nullptr, wt1, avs[0], avd[0], h8, hsc, asrc, adst, N);
    hipLaunchKernelGGL((gat_agg<4, 64>), dim3(gatgrid), dim3(256), 0, stream,
                       rowptr, csrc, h8, hsc, asrc, adst, bnS + 0, bnT + 0, x1, N);
    hipLaunchKernelGGL((gemm_fused<256, 256, false>), dim3(grid32), dim3(256), 0, stream,
                       x1, nullptr, wt2, avs[1], avd[1], h8, hsc, asrc, adst, N);
    hipLaunchKernelGGL((gat_agg<4, 64>), dim3(gatgrid), dim3(256), 0, stream,
                       rowptr, csrc, h8, hsc, asrc, adst, bnS + 256, bnT + 256, x2, N);
    hipLaunchKernelGGL((gemm_fused<256, 256, true>), dim3(grid32), dim3(256), 0, stream,
                       x1, x2, wt3, avs[2], avd[2], h8, hsc, asrc, adst, N);
    hipLaunchKernelGGL((gat_agg<4, 64>), dim3(gatgrid), dim3(256), 0, stream,
                       rowptr, csrc, h8, hsc, asrc, adst, bnS + 512, bnT + 512, x3, N);
    hipLaunchKernelGGL((gemm_fused<128, 256, false>), dim3(grid64), dim3(256), 0, stream,
                       x3, nullptr, wt4, avs[3], avd[3], h8, hsc, asrc, adst, N);
    hipLaunchKernelGGL((gat_agg<1, 128>), dim3(gatgrid), dim3(256), 0, stream,
                       rowptr, csrc, h8, hsc, asrc, adst, bnS + 768, bnT + 768, x4, N);

    hipLaunchKernelGGL(gate_gemm_kernel, dim3((N + 63) / 64), dim3(256), 0, stream,
                       x4, pw1t, pb1, pw2, pb2, gate, N);
    hipLaunchKernelGGL(pool_kernel, dim3(G), dim3(128), 0, stream, x4, gate, gstart, out);
    hipLaunchKernelGGL(gfeat_kernel, dim3(G), dim3(64), 0, stream, gfeat, gw, gb, out);
}

// Round 15
// 420.129 us; speedup vs baseline: 1.1789x; 1.1789x over previous
//
#include <hip/hip_runtime.h>
#include <cstdint>
#include <cstddef>

#define NEG_SLOPE 0.2f
#define BN_EPS 1e-5f

typedef __bf16 bf16x8 __attribute__((ext_vector_type(8)));
typedef float  f32x4  __attribute__((ext_vector_type(4)));

// single-instruction byte->float (v_cvt_f32_ubyteN)
__device__ __forceinline__ float ub0(unsigned u) { return (float)(u & 0xffu); }
__device__ __forceinline__ float ub1(unsigned u) { return (float)((u >> 8) & 0xffu); }
__device__ __forceinline__ float ub2(unsigned u) { return (float)((u >> 16) & 0xffu); }
__device__ __forceinline__ float ub3(unsigned u) { return (float)((u >> 24) & 0xffu); }

// ---------- prep: x fp32 [N][K] -> bf16 k-panels xb[k/8][N][8], Kpad=64 ----------
__global__ void conv_pad_kernel(const float* __restrict__ x, __bf16* __restrict__ xb,
                                int N, int K) {
    int i = blockIdx.x * blockDim.x + threadIdx.x;   // n*8 + panel
    int total = N * 8;
    for (; i < total; i += gridDim.x * blockDim.x) {
        int n = i >> 3, p = i & 7;
        bf16x8 v;
        #pragma unroll
        for (int j = 0; j < 8; ++j) {
            int k = p * 8 + j;
            v[j] = (k < K) ? (__bf16)x[(size_t)n * K + k] : (__bf16)0.f;
        }
        *(bf16x8*)&xb[((size_t)p * N + n) * 8] = v;
    }
}

// ---------- prep: weight k-panel transposes + BN fold, one launch ----------
// wt layout: [Kpad/8][D][8]  (lane-contiguous MFMA B-fragments).
// pw1t keeps row-major-transposed [32][128] for gate_gemm.
__global__ void prep_all_kernel(
    const float* __restrict__ W1, const float* __restrict__ W2,
    const float* __restrict__ W3, const float* __restrict__ W4,
    const float* __restrict__ PW1,
    __bf16* __restrict__ wt1, __bf16* __restrict__ wt2,
    __bf16* __restrict__ wt3, __bf16* __restrict__ wt4,
    __bf16* __restrict__ pw1t,
    const float* b1, const float* g1, const float* e1, const float* m1, const float* v1,
    const float* b2, const float* g2, const float* e2, const float* m2, const float* v2,
    const float* b3, const float* g3, const float* e3, const float* m3, const float* v3,
    const float* b4, const float* g4, const float* e4, const float* m4, const float* v4,
    float* __restrict__ bnS, float* __restrict__ bnT,   // [4][256]
    int IN) {
    int b = blockIdx.x;
    if (b >= 928) {
        int l = b - 928;
        int Dl = (l == 3) ? 128 : 256;
        int t = threadIdx.x;
        if (t < Dl) {
            const float* bias; const float* ga; const float* be;
            const float* mu;   const float* va;
            if (l == 0)      { bias = b1; ga = g1; be = e1; mu = m1; va = v1; }
            else if (l == 1) { bias = b2; ga = g2; be = e2; mu = m2; va = v2; }
            else if (l == 2) { bias = b3; ga = g3; be = e3; mu = m3; va = v3; }
            else             { bias = b4; ga = g4; be = e4; mu = m4; va = v4; }
            float S = ga[t] * rsqrtf(va[t] + BN_EPS);
            bnS[l * 256 + t] = S;
            bnT[l * 256 + t] = (bias[t] - mu[t]) * S + be[t];
        }
        return;
    }
    const float* W; __bf16* WT; int K, D, Kpad, col; bool panel = true;
    if (b < 256)      { W = W1;  WT = wt1;  K = IN;  D = 256; Kpad = 64;  col = b; }
    else if (b < 512) { W = W2;  WT = wt2;  K = 256; D = 256; Kpad = 256; col = b - 256; }
    else if (b < 768) { W = W3;  WT = wt3;  K = 256; D = 256; Kpad = 256; col = b - 512; }
    else if (b < 896) { W = W4;  WT = wt4;  K = 256; D = 128; Kpad = 256; col = b - 768; }
    else              { W = PW1; WT = pw1t; K = 128; D = 32;  Kpad = 128; col = b - 896; panel = false; }
    for (int k = threadIdx.x; k < Kpad; k += blockDim.x) {
        float v = (k < K) ? W[(size_t)k * D + col] : 0.f;
        if (panel)
            WT[((size_t)(k >> 3) * D + col) * 8 + (k & 7)] = (__bf16)v;
        else
            WT[(size_t)col * Kpad + k] = (__bf16)v;
    }
}

// ============ MFMA GEMM (32x64/wave) on k-panel inputs + fused alpha + u8 H ====
// A, A2, WT all in k-panel layout [K/8][rows][8] -> every fragment load is
// lane-contiguous (16B/lane, 16-lane groups contiguous).
template<int DCOLS, int KT, bool HAS_A2>
__global__ __launch_bounds__(256) void gemm_fused(
    const __bf16* __restrict__ A, const __bf16* __restrict__ A2,
    const __bf16* __restrict__ WT,
    const float* __restrict__ asv, const float* __restrict__ adv,
    uint8_t* __restrict__ H8, float* __restrict__ hscale,
    float* __restrict__ alpha_s, float* __restrict__ alpha_d,
    int M) {
    constexpr int NSB = DCOLS / 64;
    constexpr int RB  = (DCOLS == 256) ? 32 : 64;
    const int w    = threadIdx.x >> 6;
    const int lane = threadIdx.x & 63;
    const int l16  = lane & 15, hi4 = lane >> 4;
    const int rbase = (DCOLS == 256) ? 0 : (w >> 1) * 32;
    const int ct    = (DCOLS == 256) ? w : (w & 1);
    const int col0w = ct * 64;
    const int n0 = blockIdx.x * RB;

    f32x4 acc[2][4] = {};
    int arow[2];
    #pragma unroll
    for (int i = 0; i < 2; ++i) {
        int r = n0 + rbase + i * 16 + l16;
        arow[i] = (r < M) ? r : (M - 1);
    }

    #pragma unroll
    for (int k0 = 0; k0 < KT; k0 += 32) {
        const int panel = (k0 >> 3) + hi4;
        bf16x8 af[2], bfr[4];
        #pragma unroll
        for (int i = 0; i < 2; ++i) {
            bf16x8 v = *(const bf16x8*)&A[((size_t)panel * M + arow[i]) * 8];
            if (HAS_A2) {
                bf16x8 v2 = *(const bf16x8*)&A2[((size_t)panel * M + arow[i]) * 8];
                #pragma unroll
                for (int j = 0; j < 8; ++j) v[j] = (__bf16)((float)v[j] + (float)v2[j]);
            }
            af[i] = v;
        }
        #pragma unroll
        for (int j = 0; j < 4; ++j)
            bfr[j] = *(const bf16x8*)&WT[((size_t)panel * DCOLS + col0w + j * 16 + l16) * 8];
        #pragma unroll
        for (int i = 0; i < 2; ++i)
            #pragma unroll
            for (int j = 0; j < 4; ++j)
                acc[i][j] = __builtin_amdgcn_mfma_f32_16x16x32_bf16(
                    af[i], bfr[j], acc[i][j], 0, 0, 0);
    }

    // ---- fused alpha (partial dot over this wave's 64 cols) ----
    float asc[4], adc[4];
    #pragma unroll
    for (int j = 0; j < 4; ++j) {
        int c = col0w + j * 16 + l16;
        asc[j] = asv[c]; adc[j] = adv[c];
    }
    __shared__ float as_l[(DCOLS == 128) ? 64 : 1][2], ad_l[(DCOLS == 128) ? 64 : 1][2];
    #pragma unroll
    for (int i = 0; i < 2; ++i)
        #pragma unroll
        for (int q = 0; q < 4; ++q) {
            float ps = 0.f, pd = 0.f;
            #pragma unroll
            for (int j = 0; j < 4; ++j) {
                float v = acc[i][j][q];
                ps = fmaf(v, asc[j], ps);
                pd = fmaf(v, adc[j], pd);
            }
            #pragma unroll
            for (int o = 1; o < 16; o <<= 1) {
                ps += __shfl_xor(ps, o, 64);
                pd += __shfl_xor(pd, o, 64);
            }
            int rl = rbase + i * 16 + hi4 * 4 + q;
            if constexpr (DCOLS == 256) {
                int row = n0 + rl;
                if (l16 == 0 && row < M) {
                    alpha_s[row * 4 + w] = ps;
                    alpha_d[row * 4 + w] = pd;
                }
            } else {
                if (l16 == 0) { as_l[rl][ct] = ps; ad_l[rl][ct] = pd; }
            }
        }
    if constexpr (DCOLS == 128) {
        __syncthreads();
        int t = threadIdx.x;
        if (t < 64) {
            int row = n0 + t;
            if (row < M) {
                alpha_s[row] = as_l[t][0] + as_l[t][1];
                alpha_d[row] = ad_l[t][0] + ad_l[t][1];
            }
        }
    }

    // ---- per-wave (row, 64-col block) max|acc| -> quantize (excess-128) ----
    #pragma unroll
    for (int i = 0; i < 2; ++i)
        #pragma unroll
        for (int q = 0; q < 4; ++q) {
            float m = fabsf(acc[i][0][q]);
            #pragma unroll
            for (int j = 1; j < 4; ++j) m = fmaxf(m, fabsf(acc[i][j][q]));
            #pragma unroll
            for (int o = 1; o < 16; o <<= 1) m = fmaxf(m, __shfl_xor(m, o, 64));
            float qinv = (m > 1e-30f) ? 127.f / m : 0.f;
            int row = n0 + rbase + i * 16 + hi4 * 4 + q;
            if (row < M) {
                if (l16 == 0) hscale[row * NSB + ct] = m * (1.f / 127.f);
                #pragma unroll
                for (int j = 0; j < 4; ++j)
                    H8[(size_t)row * DCOLS + col0w + j * 16 + l16] =
                        (uint8_t)((int)rintf(acc[i][j][q] * qinv) + 128);
            }
        }
}

// ================= CSR build (once per call) =================
__global__ void deg_count_kernel(const int* __restrict__ ei, int* __restrict__ deg,
                                 int E, int Etot) {
    int e = blockIdx.x * blockDim.x + threadIdx.x;
    if (e >= Etot) return;
    int d = (e < E) ? ei[E + e] : e - E;
    atomicAdd(&deg[d], 1);
}

#define SCB 4096
__global__ __launch_bounds__(256) void scan1_kernel(const int* __restrict__ deg,
                                                    int* __restrict__ bsum, int N) {
    __shared__ int ts[256];
    const int t = threadIdx.x;
    const int base = blockIdx.x * SCB + t * 16;
    int s = 0;
    #pragma unroll
    for (int i = 0; i < 16; ++i) {
        int idx = base + i;
        if (idx < N) s += deg[idx];
    }
    ts[t] = s;
    __syncthreads();
    for (int off = 128; off > 0; off >>= 1) {
        if (t < off) ts[t] += ts[t + off];
        __syncthreads();
    }
    if (t == 0) bsum[blockIdx.x] = ts[0];
}

__global__ __launch_bounds__(256) void scan2_kernel(const int* __restrict__ bsum,
                                                    int* __restrict__ bpref, int B,
                                                    int* __restrict__ rowptrN) {
    __shared__ int sm[256];
    const int t = threadIdx.x;
    int v = (t < B) ? bsum[t] : 0;
    sm[t] = v;
    __syncthreads();
    for (int off = 1; off < 256; off <<= 1) {
        int u = (t >= off) ? sm[t - off] : 0;
        __syncthreads();
        sm[t] += u;
        __syncthreads();
    }
    if (t < B) bpref[t] = sm[t] - v;
    if (t == 255) *rowptrN = sm[255];
}

__global__ __launch_bounds__(256) void scan3_kernel(const int* __restrict__ deg,
                                                    const int* __restrict__ bpref,
                                                    int* __restrict__ rowptr,
                                                    int* __restrict__ cursor, int N) {
    __shared__ int ts[256];
    const int t = threadIdx.x;
    const int base = blockIdx.x * SCB + t * 16;
    int d[16];
    int s = 0;
    #pragma unroll
    for (int i = 0; i < 16; ++i) {
        int idx = base + i;
        d[i] = (idx < N) ? deg[idx] : 0;
        s += d[i];
    }
    ts[t] = s;
    __syncthreads();
    for (int off = 1; off < 256; off <<= 1) {
        int u = (t >= off) ? ts[t - off] : 0;
        __syncthreads();
        ts[t] += u;
        __syncthreads();
    }
    int run = bpref[blockIdx.x] + ts[t] - s;
    #pragma unroll
    for (int i = 0; i < 16; ++i) {
        int idx = base + i;
        if (idx < N) { rowptr[idx] = run; cursor[idx] = run; run += d[i]; }
    }
}

__global__ void scatter_kernel(const int* __restrict__ ei, int* __restrict__ cursor,
                               int* __restrict__ csrc, int E, int Etot) {
    int e = blockIdx.x * blockDim.x + threadIdx.x;
    if (e >= Etot) return;
    int s, d;
    if (e < E) { s = ei[e]; d = ei[E + e]; } else { s = d = e - E; }
    int pos = atomicAdd(&cursor[d], 1);
    csrc[pos] = s;
}

__global__ void gstart_kernel(const int* __restrict__ batch, int* __restrict__ gstart,
                              int N, int G) {
    int n = blockIdx.x * blockDim.x + threadIdx.x;
    if (n >= N) return;
    int b = batch[n];
    if (n == 0) { for (int g = 0; g <= b; ++g) gstart[g] = 0; }
    else {
        int bp = batch[n - 1];
        for (int g = bp + 1; g <= b; ++g) gstart[g] = n;
    }
    if (n == N - 1) { for (int g = b + 1; g <= G; ++g) gstart[g] = N; }
}

// ============ GAT edge phase: TWO nodes per wave, per-block-scale u8 gather ====
// OUTP=true -> write output in k-panel layout [D/8][N][8] (for next layer's GEMM).
template<int HEADS, int C, bool OUTP>
__global__ __launch_bounds__(256) void gat_agg(
    const int* __restrict__ rowptr, const int* __restrict__ csrc,
    const uint8_t* __restrict__ hf, const float* __restrict__ hscale,
    const float* __restrict__ asrc, const float* __restrict__ adst,
    const float* __restrict__ bnS, const float* __restrict__ bnT,
    __bf16* __restrict__ out, int N) {
    constexpr int D   = HEADS * C;
    constexpr int NSB = D / 64;
    constexpr int LPE = D / 8;
    constexpr int EPH = 32 / LPE;

    const int wid  = threadIdx.x >> 6;
    const int lane = threadIdx.x & 63;
    const int half = lane >> 5;
    const int sl   = lane & 31;

    __shared__ int   soff[4][2][32];
    __shared__ float pal[4][2][32][NSB];

    const int npairs = (N + 1) >> 1;

    for (int pair = blockIdx.x * 4 + wid; pair < npairs; pair += gridDim.x * 4) {
        const int node = pair * 2 + half;
        const bool valid = node < N;
        const int beg = valid ? rowptr[node] : 0;
        const int end = valid ? rowptr[node + 1] : 0;
        const int deg = end - beg;

        const int grp = (EPH == 1) ? 0 : (sl >> 4);
        const int c0  = (EPH == 1) ? sl * 8 : (sl & 15) * 8;
        const int sb  = c0 >> 6;
        const uint8_t* hb = hf + c0;

        float ad[HEADS];
        #pragma unroll
        for (int h = 0; h < HEADS; ++h) ad[h] = valid ? adst[node * HEADS + h] : 0.f;

        float acc8[8] = {};
        float psum = 0.f;

        auto fmau8 = [&](uint2 v, float q) {
            acc8[0] = fmaf(ub0(v.x), q, acc8[0]);
            acc8[1] = fmaf(ub1(v.x), q, acc8[1]);
            acc8[2] = fmaf(ub2(v.x), q, acc8[2]);
            acc8[3] = fmaf(ub3(v.x), q, acc8[3]);
            acc8[4] = fmaf(ub0(v.y), q, acc8[4]);
            acc8[5] = fmaf(ub1(v.y), q, acc8[5]);
            acc8[6] = fmaf(ub2(v.y), q, acc8[6]);
            acc8[7] = fmaf(ub3(v.y), q, acc8[7]);
        };

        auto agg_chunk = [&](int cnt) {
            int e = 0;
            for (; e + 4 * EPH <= cnt; e += 4 * EPH) {
                int o0 = soff[wid][half][e + 0 * EPH + grp];
                int o1 = soff[wid][half][e + 1 * EPH + grp];
                int o2 = soff[wid][half][e + 2 * EPH + grp];
                int o3 = soff[wid][half][e + 3 * EPH + grp];
                float q0 = pal[wid][half][e + 0 * EPH + grp][sb];
                float q1 = pal[wid][half][e + 1 * EPH + grp][sb];
                float q2 = pal[wid][half][e + 2 * EPH + grp][sb];
                float q3 = pal[wid][half][e + 3 * EPH + grp][sb];
                uint2 v0 = *(const uint2*)(hb + o0);
                uint2 v1 = *(const uint2*)(hb + o1);
                uint2 v2 = *(const uint2*)(hb + o2);
                uint2 v3 = *(const uint2*)(hb + o3);
                psum += (q0 + q1) + (q2 + q3);
                fmau8(v0, q0); fmau8(v1, q1); fmau8(v2, q2); fmau8(v3, q3);
            }
            for (; e + EPH <= cnt; e += EPH) {
                int o0 = soff[wid][half][e + grp];
                float q0 = pal[wid][half][e + grp][sb];
                uint2 v0 = *(const uint2*)(hb + o0);
                psum += q0;
                fmau8(v0, q0);
            }
            if (EPH == 2 && e < cnt) {
                int r = cnt - e;
                int idx = (grp < r) ? e + grp : e;
                int o0 = soff[wid][half][idx];
                float q0 = (grp < r) ? pal[wid][half][idx][sb] : 0.f;
                uint2 v0 = *(const uint2*)(hb + o0);
                psum += q0;
                fmau8(v0, q0);
            }
        };

        if (deg <= 32) {
            const bool act = sl < deg;
            int msrc = act ? csrc[beg + sl] : 0;
            float lv[HEADS];
            if constexpr (HEADS == 4) {
                float4 a4 = ((const float4*)asrc)[msrc];
                lv[0] = a4.x; lv[1] = a4.y; lv[2] = a4.z; lv[3] = a4.w;
            } else {
                lv[0] = asrc[msrc];
            }
            float pe_[HEADS];
            #pragma unroll
            for (int h = 0; h < HEADS; ++h) {
                float v;
                if (act) { v = lv[h] + ad[h]; v = v > 0.f ? v : NEG_SLOPE * v; }
                else v = -INFINITY;
                float mx = v;
                #pragma unroll
                for (int o = 1; o < 32; o <<= 1) mx = fmaxf(mx, __shfl_xor(mx, o, 64));
                float pe = act ? __expf(v - mx) : 0.f;
                float ps = pe;
                #pragma unroll
                for (int o = 1; o < 32; o <<= 1) ps += __shfl_xor(ps, o, 64);
                pe_[h] = pe * (1.f / (ps + 1e-16f));
            }
            soff[wid][half][sl] = msrc * D;
            if constexpr (HEADS == 4) {
                float4 hs = act ? ((const float4*)hscale)[msrc]
                                : make_float4(0.f, 0.f, 0.f, 0.f);
                *(float4*)&pal[wid][half][sl][0] =
                    make_float4(pe_[0] * hs.x, pe_[1] * hs.y, pe_[2] * hs.z, pe_[3] * hs.w);
            } else {
                float2 hs = act ? ((const float2*)hscale)[msrc] : make_float2(0.f, 0.f);
                *(float2*)&pal[wid][half][sl][0] = make_float2(pe_[0] * hs.x, pe_[0] * hs.y);
            }
            asm volatile("s_waitcnt lgkmcnt(0)" ::: "memory");
            agg_chunk(deg);
        } else {
            float mx[HEADS], sm[HEADS], inv[HEADS];
            #pragma unroll
            for (int h = 0; h < HEADS; ++h) mx[h] = -INFINITY;
            for (int j = beg + sl; j < end; j += 32) {
                int s = csrc[j];
                #pragma unroll
                for (int h = 0; h < HEADS; ++h) {
                    float v = asrc[s * HEADS + h] + ad[h];
                    v = v > 0.f ? v : NEG_SLOPE * v;
                    mx[h] = fmaxf(mx[h], v);
                }
            }
            #pragma unroll
            for (int h = 0; h < HEADS; ++h) {
                #pragma unroll
                for (int o = 1; o < 32; o <<= 1) mx[h] = fmaxf(mx[h], __shfl_xor(mx[h], o, 64));
                sm[h] = 0.f;
            }
            for (int j = beg + sl; j < end; j += 32) {
                int s = csrc[j];
                #pragma unroll
                for (int h = 0; h < HEADS; ++h) {
                    float v = asrc[s * HEADS + h] + ad[h];
                    v = v > 0.f ? v : NEG_SLOPE * v;
                    sm[h] += __expf(v - mx[h]);
                }
            }
            #pragma unroll
            for (int h = 0; h < HEADS; ++h) {
                #pragma unroll
                for (int o = 1; o < 32; o <<= 1) sm[h] += __shfl_xor(sm[h], o, 64);
                inv[h] = 1.f / (sm[h] + 1e-16f);
            }
            for (int base2 = beg; base2 < end; base2 += 32) {
                int ne = min(32, end - base2);
                bool act2 = sl < ne;
                int msrc = csrc[base2 + (act2 ? sl : 0)];
                soff[wid][half][sl] = msrc * D;
                if constexpr (HEADS == 4) {
                    float4 hs = act2 ? ((const float4*)hscale)[msrc]
                                     : make_float4(0.f, 0.f, 0.f, 0.f);
                    float hsv[4] = {hs.x, hs.y, hs.z, hs.w};
                    #pragma unroll
                    for (int h = 0; h < 4; ++h) {
                        float pv = 0.f;
                        if (act2) {
                            float v = asrc[msrc * 4 + h] + ad[h];
                            v = v > 0.f ? v : NEG_SLOPE * v;
                            pv = __expf(v - mx[h]) * inv[h];
                        }
                        pal[wid][half][sl][h] = pv * hsv[h];
                    }
                } else {
                    float2 hs = act2 ? ((const float2*)hscale)[msrc] : make_float2(0.f, 0.f);
                    float pv = 0.f;
                    if (act2) {
                        float v = asrc[msrc] + ad[0];
                        v = v > 0.f ? v : NEG_SLOPE * v;
                        pv = __expf(v - mx[0]) * inv[0];
                    }
                    pal[wid][half][sl][0] = pv * hs.x;
                    pal[wid][half][sl][1] = pv * hs.y;
                }
                asm volatile("s_waitcnt lgkmcnt(0)" ::: "memory");
                agg_chunk(ne);
                asm volatile("s_waitcnt lgkmcnt(0)" ::: "memory");
            }
        }

        if constexpr (EPH == 2) {
            #pragma unroll
            for (int i = 0; i < 8; ++i)
                acc8[i] += __shfl_xor(acc8[i], 16, 64);
            psum += __shfl_xor(psum, 16, 64);
        }

        // ---- epilogue: excess-128 fix + folded BN + ReLU -> bf16 ----
        if (valid && (EPH == 1 || sl < 16)) {
            float4 Sa = *(const float4*)&bnS[c0];
            float4 Sb = *(const float4*)&bnS[c0 + 4];
            float4 Ta = *(const float4*)&bnT[c0];
            float4 Tb = *(const float4*)&bnT[c0 + 4];
            float S8[8] = {Sa.x, Sa.y, Sa.z, Sa.w, Sb.x, Sb.y, Sb.z, Sb.w};
            float T8[8] = {Ta.x, Ta.y, Ta.z, Ta.w, Tb.x, Tb.y, Tb.z, Tb.w};
            bf16x8 ov;
            #pragma unroll
            for (int i = 0; i < 8; ++i) {
                float v = fmaf(acc8[i] - 128.f * psum, S8[i], T8[i]);
                ov[i] = (__bf16)fmaxf(v, 0.f);
            }
            if constexpr (OUTP)
                *(bf16x8*)&out[((size_t)(c0 >> 3) * N + node) * 8] = ov;   // k-panel
            else
                *(bf16x8*)&out[(size_t)node * D + c0] = ov;                // row-major
        }
    }
}

// ---------- gate MLP via MFMA (x4 row-major) ----------
__global__ __launch_bounds__(256) void gate_gemm_kernel(
    const __bf16* __restrict__ x4, const __bf16* __restrict__ pw1t,
    const float* __restrict__ pb1, const float* __restrict__ pw2,
    const float* __restrict__ pb2, float* __restrict__ gate, int N) {
    const int w    = threadIdx.x >> 6;
    const int lane = threadIdx.x & 63;
    const int l16  = lane & 15, hi4 = lane >> 4;
    const int n0 = (blockIdx.x * 4 + w) * 16;
    if (n0 >= N) return;
    const int arow = min(n0 + l16, N - 1);
    f32x4 acc[2] = {};
    #pragma unroll
    for (int k0 = 0; k0 < 128; k0 += 32) {
        bf16x8 af = *(const bf16x8*)&x4[(size_t)arow * 128 + k0 + hi4 * 8];
        bf16x8 b0 = *(const bf16x8*)&pw1t[(size_t)l16 * 128 + k0 + hi4 * 8];
        bf16x8 b1 = *(const bf16x8*)&pw1t[(size_t)(16 + l16) * 128 + k0 + hi4 * 8];
        acc[0] = __builtin_amdgcn_mfma_f32_16x16x32_bf16(af, b0, acc[0], 0, 0, 0);
        acc[1] = __builtin_amdgcn_mfma_f32_16x16x32_bf16(af, b1, acc[1], 0, 0, 0);
    }
    float pb1a = pb1[l16], pb1b = pb1[16 + l16];
    float w2a = pw2[l16], w2b = pw2[16 + l16];
    #pragma unroll
    for (int q = 0; q < 4; ++q) {
        float g = fmaxf(acc[0][q] + pb1a, 0.f) * w2a +
                  fmaxf(acc[1][q] + pb1b, 0.f) * w2b;
        #pragma unroll
        for (int o = 1; o < 16; o <<= 1) g += __shfl_xor(g, o, 64);
        int row = n0 + hi4 * 4 + q;
        if (l16 == 0 && row < N) gate[row] = g + pb2[0];
    }
}

// ---------- block-per-graph pooling ----------
__global__ __launch_bounds__(128) void pool_kernel(
    const __bf16* __restrict__ x4, const float* __restrict__ gate,
    const int* __restrict__ gstart, float* __restrict__ out) {
    const int g = blockIdx.x;
    const int t = threadIdx.x;
    const int beg = gstart[g], end = gstart[g + 1];
    __shared__ float red[128];
    __shared__ float wbuf[128];
    float m = -INFINITY;
    for (int n = beg + t; n < end; n += 128) m = fmaxf(m, gate[n]);
    red[t] = m; __syncthreads();
    for (int off = 64; off > 0; off >>= 1) {
        if (t < off) red[t] = fmaxf(red[t], red[t + off]);
        __syncthreads();
    }
    m = red[0]; __syncthreads();
    float s = 0.f;
    for (int n = beg + t; n < end; n += 128) s += expf(gate[n] - m);
    red[t] = s; __syncthreads();
    for (int off = 64; off > 0; off >>= 1) {
        if (t < off) red[t] += red[t + off];
        __syncthreads();
    }
    const float inv = 1.f / (red[0] + 1e-16f);
    __syncthreads();
    float acc = 0.f;
    for (int base = beg; base < end; base += 128) {
        int ne = min(128, end - base);
        if (t < ne) wbuf[t] = expf(gate[base + t] - m) * inv;
        __syncthreads();
        for (int i = 0; i < ne; ++i)
            acc = fmaf(wbuf[i], (float)x4[(size_t)(base + i) * 128 + t], acc);
        __syncthreads();
    }
    out[(size_t)g * 160 + t] = acc;
}

// ---------- global-feature MLP ----------
__global__ void gfeat_kernel(const float* __restrict__ gfeat,
                             const float* __restrict__ gw, const float* __restrict__ gb,
                             float* __restrict__ out) {
    const int g = blockIdx.x;
    const int k = threadIdx.x;
    if (k < 32) {
        float t = gb[k];
        #pragma unroll
        for (int j = 0; j < 7; ++j) t = fmaf(gfeat[g * 7 + j], gw[j * 32 + k], t);
        out[(size_t)g * 160 + 128 + k] = fmaxf(t, 0.f);
    }
}

// ==========================================================================
extern "C" void kernel_launch(void* const* d_in, const int* in_sizes, int n_in,
                              void* d_out, int out_size, void* d_ws, size_t ws_size,
                              hipStream_t stream) {
    const float* x      = (const float*)d_in[0];
    const int*   ei     = (const int*)  d_in[1];
    const int*   batch  = (const int*)  d_in[2];
    const float* gfeat  = (const float*)d_in[3];

    const int N    = in_sizes[2];
    const int E    = in_sizes[1] / 2;
    const int G    = in_sizes[3] / 7;
    const int IN   = in_sizes[0] / N;
    const int Etot = E + N;

    const float* W[4];  const float* avs[4]; const float* avd[4]; const float* bi[4];
    const float* ga[4]; const float* be[4];  const float* mu[4];  const float* va[4];
    for (int l = 0; l < 4; ++l) {
        int o = 4 + 8 * l;
        W[l]   = (const float*)d_in[o + 0];
        avs[l] = (const float*)d_in[o + 1];
        avd[l] = (const float*)d_in[o + 2];
        bi[l]  = (const float*)d_in[o + 3];
        ga[l]  = (const float*)d_in[o + 4];
        be[l]  = (const float*)d_in[o + 5];
        mu[l]  = (const float*)d_in[o + 6];
        va[l]  = (const float*)d_in[o + 7];
    }
    const float* pw1 = (const float*)d_in[36];
    const float* pb1 = (const float*)d_in[37];
    const float* pw2 = (const float*)d_in[38];
    const float* pb2 = (const float*)d_in[39];
    const float* gw  = (const float*)d_in[40];
    const float* gb  = (const float*)d_in[41];

    float* out = (float*)d_out;

    float* ws = (float*)d_ws;
    __bf16* xb = (__bf16*)ws; ws += (size_t)N * 32;      // panels [8][N][8]
    uint8_t* h8 = (uint8_t*)ws; ws += (size_t)N * 64;
    float* hsc = ws;  ws += (size_t)N * 4;               // [N][NSB<=4]
    __bf16* x1 = (__bf16*)ws; ws += (size_t)N * 128;     // panels [32][N][8]
    __bf16* x2 = (__bf16*)ws; ws += (size_t)N * 128;
    __bf16* x3 = (__bf16*)ws; ws += (size_t)N * 128;
    __bf16* wt1 = (__bf16*)ws; ws += 256 * 64 / 2;       // panels [8][256][8]
    __bf16* wt2 = (__bf16*)ws; ws += 256 * 256 / 2;      // panels [32][256][8]
    __bf16* wt3 = (__bf16*)ws; ws += 256 * 256 / 2;
    __bf16* wt4 = (__bf16*)ws; ws += 128 * 256 / 2;      // panels [32][128][8]
    __bf16* pw1t = (__bf16*)ws; ws += 32 * 128 / 2;      // row-major [32][128]
    float* bnS = ws; ws += 4 * 256;
    float* bnT = ws; ws += 4 * 256;
    float* asrc = ws;  ws += (size_t)N * 4;
    float* adst = ws;  ws += (size_t)N * 4;
    float* gate = ws;  ws += N;
    int* deg    = (int*)ws; ws += N;
    int* cursor = (int*)ws; ws += N;
    int* rowptr = (int*)ws; ws += (N + 1);
    int* csrc   = (int*)ws; ws += Etot;
    int* gstart = (int*)ws; ws += (G + 1);
    int* bsum   = (int*)ws; ws += 256;
    int* bpref  = (int*)ws; ws += 256;
    __bf16* x4 = x1;    // x1 panels fully consumed by layer-3 gemm before x4 write

    const int SB = (N + SCB - 1) / SCB;

    hipLaunchKernelGGL(conv_pad_kernel, dim3(512), dim3(256), 0, stream, x, xb, N, IN);
    hipLaunchKernelGGL(prep_all_kernel, dim3(932), dim3(256), 0, stream,
                       W[0], W[1], W[2], W[3], pw1, wt1, wt2, wt3, wt4, pw1t,
                       bi[0], ga[0], be[0], mu[0], va[0],
                       bi[1], ga[1], be[1], mu[1], va[1],
                       bi[2], ga[2], be[2], mu[2], va[2],
                       bi[3], ga[3], be[3], mu[3], va[3],
                       bnS, bnT, IN);

    hipMemsetAsync(deg, 0, (size_t)N * 4, stream);
    hipLaunchKernelGGL(deg_count_kernel, dim3((Etot + 255) / 256), dim3(256), 0, stream,
                       ei, deg, E, Etot);
    hipLaunchKernelGGL(scan1_kernel, dim3(SB), dim3(256), 0, stream, deg, bsum, N);
    hipLaunchKernelGGL(scan2_kernel, dim3(1), dim3(256), 0, stream, bsum, bpref, SB,
                       &rowptr[N]);
    hipLaunchKernelGGL(scan3_kernel, dim3(SB), dim3(256), 0, stream, deg, bpref,
                       rowptr, cursor, N);
    hipLaunchKernelGGL(scatter_kernel, dim3((Etot + 255) / 256), dim3(256), 0, stream,
                       ei, cursor, csrc, E, Etot);
    hipLaunchKernelGGL(gstart_kernel, dim3((N + 255) / 256), dim3(256), 0, stream,
                       batch, gstart, N, G);

    const int grid32  = (N + 31) / 32;
    const int grid64  = (N + 63) / 64;
    const int gatgrid = 2048;

    hipLaunchKernelGGL((gemm_fused<256, 64, false>), dim3(grid32), dim3(256), 0, stream,
                       xb, nullptr, wt1, avs[0], avd[0], h8, hsc, asrc, adst, N);
    hipLaunchKernelGGL((gat_agg<4, 64, true>), dim3(gatgrid), dim3(256), 0, stream,
                       rowptr, csrc, h8, hsc, asrc, adst, bnS + 0, bnT + 0, x1, N);
    hipLaunchKernelGGL((gemm_fused<256, 256, false>), dim3(grid32), dim3(256), 0, stream,
                       x1, nullptr, wt2, avs[1], avd[1], h8, hsc, asrc, adst, N);
    hipLaunchKernelGGL((gat_agg<4, 64, true>), dim3(gatgrid), dim3(256), 0, stream,
                       rowptr, csrc, h8, hsc, asrc, adst, bnS + 256, bnT + 256, x2, N);
    hipLaunchKernelGGL((gemm_fused<256, 256, true>), dim3(grid32), dim3(256), 0, stream,
                       x1, x2, wt3, avs[2], avd[2], h8, hsc, asrc, adst, N);
    hipLaunchKernelGGL((gat_agg<4, 64, true>), dim3(gatgrid), dim3(256), 0, stream,
                       rowptr, csrc, h8, hsc, asrc, adst, bnS + 512, bnT + 512, x3, N);
    hipLaunchKernelGGL((gemm_fused<128, 256, false>), dim3(grid64), dim3(256), 0, stream,
                       x3, nullptr, wt4, avs[3], avd[3], h8, hsc, asrc, adst, N);
    hipLaunchKernelGGL((gat_agg<1, 128, false>), dim3(gatgrid), dim3(256), 0, stream,
                       rowptr, csrc, h8, hsc, asrc, adst, bnS + 768, bnT + 768, x4, N);

    hipLaunchKernelGGL(gate_gemm_kernel, dim3((N + 63) / 64), dim3(256), 0, stream,
                       x4, pw1t, pb1, pw2, pb2, gate, N);
    hipLaunchKernelGGL(pool_kernel, dim3(G), dim3(128), 0, stream, x4, gate, gstart, out);
    hipLaunchKernelGGL(gfeat_kernel, dim3(G), dim3(64), 0, stream, gfeat, gw, gb, out);
}

// Round 16
// 410.527 us; speedup vs baseline: 1.2064x; 1.0234x over previous
//
#include <hip/hip_runtime.h>
#include <cstdint>
#include <cstddef>

#define NEG_SLOPE 0.2f
#define BN_EPS 1e-5f

typedef __bf16 bf16x8 __attribute__((ext_vector_type(8)));
typedef float  f32x4  __attribute__((ext_vector_type(4)));

// single-instruction byte->float (v_cvt_f32_ubyteN)
__device__ __forceinline__ float ub0(unsigned u) { return (float)(u & 0xffu); }
__device__ __forceinline__ float ub1(unsigned u) { return (float)((u >> 8) & 0xffu); }
__device__ __forceinline__ float ub2(unsigned u) { return (float)((u >> 16) & 0xffu); }
__device__ __forceinline__ float ub3(unsigned u) { return (float)((u >> 24) & 0xffu); }

// ---------- prep: x fp32 [N][K] -> bf16 k-panels xb[k/8][N][8], Kpad=64 ----------
__global__ void conv_pad_kernel(const float* __restrict__ x, __bf16* __restrict__ xb,
                                int N, int K) {
    int i = blockIdx.x * blockDim.x + threadIdx.x;   // n*8 + panel
    int total = N * 8;
    for (; i < total; i += gridDim.x * blockDim.x) {
        int n = i >> 3, p = i & 7;
        bf16x8 v;
        #pragma unroll
        for (int j = 0; j < 8; ++j) {
            int k = p * 8 + j;
            v[j] = (k < K) ? (__bf16)x[(size_t)n * K + k] : (__bf16)0.f;
        }
        *(bf16x8*)&xb[((size_t)p * N + n) * 8] = v;
    }
}

// ---------- prep: weight k-panel transposes + BN fold, one launch ----------
__global__ void prep_all_kernel(
    const float* __restrict__ W1, const float* __restrict__ W2,
    const float* __restrict__ W3, const float* __restrict__ W4,
    const float* __restrict__ PW1,
    __bf16* __restrict__ wt1, __bf16* __restrict__ wt2,
    __bf16* __restrict__ wt3, __bf16* __restrict__ wt4,
    __bf16* __restrict__ pw1t,
    const float* b1, const float* g1, const float* e1, const float* m1, const float* v1,
    const float* b2, const float* g2, const float* e2, const float* m2, const float* v2,
    const float* b3, const float* g3, const float* e3, const float* m3, const float* v3,
    const float* b4, const float* g4, const float* e4, const float* m4, const float* v4,
    float* __restrict__ bnS, float* __restrict__ bnT,   // [4][256]
    int IN) {
    int b = blockIdx.x;
    if (b >= 928) {
        int l = b - 928;
        int Dl = (l == 3) ? 128 : 256;
        int t = threadIdx.x;
        if (t < Dl) {
            const float* bias; const float* ga; const float* be;
            const float* mu;   const float* va;
            if (l == 0)      { bias = b1; ga = g1; be = e1; mu = m1; va = v1; }
            else if (l == 1) { bias = b2; ga = g2; be = e2; mu = m2; va = v2; }
            else if (l == 2) { bias = b3; ga = g3; be = e3; mu = m3; va = v3; }
            else             { bias = b4; ga = g4; be = e4; mu = m4; va = v4; }
            float S = ga[t] * rsqrtf(va[t] + BN_EPS);
            bnS[l * 256 + t] = S;
            bnT[l * 256 + t] = (bias[t] - mu[t]) * S + be[t];
        }
        return;
    }
    const float* W; __bf16* WT; int K, D, Kpad, col; bool panel = true;
    if (b < 256)      { W = W1;  WT = wt1;  K = IN;  D = 256; Kpad = 64;  col = b; }
    else if (b < 512) { W = W2;  WT = wt2;  K = 256; D = 256; Kpad = 256; col = b - 256; }
    else if (b < 768) { W = W3;  WT = wt3;  K = 256; D = 256; Kpad = 256; col = b - 512; }
    else if (b < 896) { W = W4;  WT = wt4;  K = 256; D = 128; Kpad = 256; col = b - 768; }
    else              { W = PW1; WT = pw1t; K = 128; D = 32;  Kpad = 128; col = b - 896; panel = false; }
    for (int k = threadIdx.x; k < Kpad; k += blockDim.x) {
        float v = (k < K) ? W[(size_t)k * D + col] : 0.f;
        if (panel)
            WT[((size_t)(k >> 3) * D + col) * 8 + (k & 7)] = (__bf16)v;
        else
            WT[(size_t)col * Kpad + k] = (__bf16)v;
    }
}

// ============ MFMA GEMM (32x64/wave) on k-panel inputs + fused alpha + u8 H ====
template<int DCOLS, int KT, bool HAS_A2>
__global__ __launch_bounds__(256) void gemm_fused(
    const __bf16* __restrict__ A, const __bf16* __restrict__ A2,
    const __bf16* __restrict__ WT,
    const float* __restrict__ asv, const float* __restrict__ adv,
    uint8_t* __restrict__ H8, float* __restrict__ hscale,
    float* __restrict__ alpha_s, float* __restrict__ alpha_d,
    int M) {
    constexpr int NSB = DCOLS / 64;
    constexpr int RB  = (DCOLS == 256) ? 32 : 64;
    const int w    = threadIdx.x >> 6;
    const int lane = threadIdx.x & 63;
    const int l16  = lane & 15, hi4 = lane >> 4;
    const int rbase = (DCOLS == 256) ? 0 : (w >> 1) * 32;
    const int ct    = (DCOLS == 256) ? w : (w & 1);
    const int col0w = ct * 64;
    const int n0 = blockIdx.x * RB;

    f32x4 acc[2][4] = {};
    int arow[2];
    #pragma unroll
    for (int i = 0; i < 2; ++i) {
        int r = n0 + rbase + i * 16 + l16;
        arow[i] = (r < M) ? r : (M - 1);
    }

    #pragma unroll
    for (int k0 = 0; k0 < KT; k0 += 32) {
        const int panel = (k0 >> 3) + hi4;
        bf16x8 af[2], bfr[4];
        #pragma unroll
        for (int i = 0; i < 2; ++i) {
            bf16x8 v = *(const bf16x8*)&A[((size_t)panel * M + arow[i]) * 8];
            if (HAS_A2) {
                bf16x8 v2 = *(const bf16x8*)&A2[((size_t)panel * M + arow[i]) * 8];
                #pragma unroll
                for (int j = 0; j < 8; ++j) v[j] = (__bf16)((float)v[j] + (float)v2[j]);
            }
            af[i] = v;
        }
        #pragma unroll
        for (int j = 0; j < 4; ++j)
            bfr[j] = *(const bf16x8*)&WT[((size_t)panel * DCOLS + col0w + j * 16 + l16) * 8];
        #pragma unroll
        for (int i = 0; i < 2; ++i)
            #pragma unroll
            for (int j = 0; j < 4; ++j)
                acc[i][j] = __builtin_amdgcn_mfma_f32_16x16x32_bf16(
                    af[i], bfr[j], acc[i][j], 0, 0, 0);
    }

    // ---- fused alpha (partial dot over this wave's 64 cols) ----
    float asc[4], adc[4];
    #pragma unroll
    for (int j = 0; j < 4; ++j) {
        int c = col0w + j * 16 + l16;
        asc[j] = asv[c]; adc[j] = adv[c];
    }
    __shared__ float as_l[(DCOLS == 128) ? 64 : 1][2], ad_l[(DCOLS == 128) ? 64 : 1][2];
    #pragma unroll
    for (int i = 0; i < 2; ++i)
        #pragma unroll
        for (int q = 0; q < 4; ++q) {
            float ps = 0.f, pd = 0.f;
            #pragma unroll
            for (int j = 0; j < 4; ++j) {
                float v = acc[i][j][q];
                ps = fmaf(v, asc[j], ps);
                pd = fmaf(v, adc[j], pd);
            }
            #pragma unroll
            for (int o = 1; o < 16; o <<= 1) {
                ps += __shfl_xor(ps, o, 64);
                pd += __shfl_xor(pd, o, 64);
            }
            int rl = rbase + i * 16 + hi4 * 4 + q;
            if constexpr (DCOLS == 256) {
                int row = n0 + rl;
                if (l16 == 0 && row < M) {
                    alpha_s[row * 4 + w] = ps;
                    alpha_d[row * 4 + w] = pd;
                }
            } else {
                if (l16 == 0) { as_l[rl][ct] = ps; ad_l[rl][ct] = pd; }
            }
        }
    if constexpr (DCOLS == 128) {
        __syncthreads();
        int t = threadIdx.x;
        if (t < 64) {
            int row = n0 + t;
            if (row < M) {
                alpha_s[row] = as_l[t][0] + as_l[t][1];
                alpha_d[row] = ad_l[t][0] + ad_l[t][1];
            }
        }
    }

    // ---- per-wave (row, 64-col block) max|acc| -> quantize (excess-128) ----
    #pragma unroll
    for (int i = 0; i < 2; ++i)
        #pragma unroll
        for (int q = 0; q < 4; ++q) {
            float m = fabsf(acc[i][0][q]);
            #pragma unroll
            for (int j = 1; j < 4; ++j) m = fmaxf(m, fabsf(acc[i][j][q]));
            #pragma unroll
            for (int o = 1; o < 16; o <<= 1) m = fmaxf(m, __shfl_xor(m, o, 64));
            float qinv = (m > 1e-30f) ? 127.f / m : 0.f;
            int row = n0 + rbase + i * 16 + hi4 * 4 + q;
            if (row < M) {
                if (l16 == 0) hscale[row * NSB + ct] = m * (1.f / 127.f);
                #pragma unroll
                for (int j = 0; j < 4; ++j)
                    H8[(size_t)row * DCOLS + col0w + j * 16 + l16] =
                        (uint8_t)((int)rintf(acc[i][j][q] * qinv) + 128);
            }
        }
}

// ================= CSR build (once per call) =================
__global__ void deg_count_kernel(const int* __restrict__ ei, int* __restrict__ deg,
                                 int E, int Etot) {
    int e = blockIdx.x * blockDim.x + threadIdx.x;
    if (e >= Etot) return;
    int d = (e < E) ? ei[E + e] : e - E;
    atomicAdd(&deg[d], 1);
}

#define SCB 4096
__global__ __launch_bounds__(256) void scan1_kernel(const int* __restrict__ deg,
                                                    int* __restrict__ bsum, int N) {
    __shared__ int ts[256];
    const int t = threadIdx.x;
    const int base = blockIdx.x * SCB + t * 16;
    int s = 0;
    #pragma unroll
    for (int i = 0; i < 16; ++i) {
        int idx = base + i;
        if (idx < N) s += deg[idx];
    }
    ts[t] = s;
    __syncthreads();
    for (int off = 128; off > 0; off >>= 1) {
        if (t < off) ts[t] += ts[t + off];
        __syncthreads();
    }
    if (t == 0) bsum[blockIdx.x] = ts[0];
}

__global__ __launch_bounds__(256) void scan2_kernel(const int* __restrict__ bsum,
                                                    int* __restrict__ bpref, int B,
                                                    int* __restrict__ rowptrN) {
    __shared__ int sm[256];
    const int t = threadIdx.x;
    int v = (t < B) ? bsum[t] : 0;
    sm[t] = v;
    __syncthreads();
    for (int off = 1; off < 256; off <<= 1) {
        int u = (t >= off) ? sm[t - off] : 0;
        __syncthreads();
        sm[t] += u;
        __syncthreads();
    }
    if (t < B) bpref[t] = sm[t] - v;
    if (t == 255) *rowptrN = sm[255];
}

__global__ __launch_bounds__(256) void scan3_kernel(const int* __restrict__ deg,
                                                    const int* __restrict__ bpref,
                                                    int* __restrict__ rowptr,
                                                    int* __restrict__ cursor, int N) {
    __shared__ int ts[256];
    const int t = threadIdx.x;
    const int base = blockIdx.x * SCB + t * 16;
    int d[16];
    int s = 0;
    #pragma unroll
    for (int i = 0; i < 16; ++i) {
        int idx = base + i;
        d[i] = (idx < N) ? deg[idx] : 0;
        s += d[i];
    }
    ts[t] = s;
    __syncthreads();
    for (int off = 1; off < 256; off <<= 1) {
        int u = (t >= off) ? ts[t - off] : 0;
        __syncthreads();
        ts[t] += u;
        __syncthreads();
    }
    int run = bpref[blockIdx.x] + ts[t] - s;
    #pragma unroll
    for (int i = 0; i < 16; ++i) {
        int idx = base + i;
        if (idx < N) { rowptr[idx] = run; cursor[idx] = run; run += d[i]; }
    }
}

__global__ void scatter_kernel(const int* __restrict__ ei, int* __restrict__ cursor,
                               int* __restrict__ csrc, int E, int Etot) {
    int e = blockIdx.x * blockDim.x + threadIdx.x;
    if (e >= Etot) return;
    int s, d;
    if (e < E) { s = ei[e]; d = ei[E + e]; } else { s = d = e - E; }
    int pos = atomicAdd(&cursor[d], 1);
    csrc[pos] = s;
}

__global__ void gstart_kernel(const int* __restrict__ batch, int* __restrict__ gstart,
                              int N, int G) {
    int n = blockIdx.x * blockDim.x + threadIdx.x;
    if (n >= N) return;
    int b = batch[n];
    if (n == 0) { for (int g = 0; g <= b; ++g) gstart[g] = 0; }
    else {
        int bp = batch[n - 1];
        for (int g = bp + 1; g <= b; ++g) gstart[g] = n;
    }
    if (n == N - 1) { for (int g = b + 1; g <= G; ++g) gstart[g] = N; }
}

// ============ GAT edge phase: TWO nodes per wave, 8-deep batched u8 gather ====
// pal/soff are zero-filled for all 32 slots, so aggregation runs uniform 8-deep
// steps rounded up (padding slots: q=0, read cached row 0 -> exact, no tail).
template<int HEADS, int C, bool OUTP>
__global__ __launch_bounds__(256) void gat_agg(
    const int* __restrict__ rowptr, const int* __restrict__ csrc,
    const uint8_t* __restrict__ hf, const float* __restrict__ hscale,
    const float* __restrict__ asrc, const float* __restrict__ adst,
    const float* __restrict__ bnS, const float* __restrict__ bnT,
    __bf16* __restrict__ out, int N) {
    constexpr int D   = HEADS * C;
    constexpr int NSB = D / 64;
    constexpr int LPE = D / 8;
    constexpr int EPH = 32 / LPE;

    const int wid  = threadIdx.x >> 6;
    const int lane = threadIdx.x & 63;
    const int half = lane >> 5;
    const int sl   = lane & 31;

    __shared__ int   soff[4][2][32];
    __shared__ float pal[4][2][32][NSB];

    const int npairs = (N + 1) >> 1;

    for (int pair = blockIdx.x * 4 + wid; pair < npairs; pair += gridDim.x * 4) {
        const int node = pair * 2 + half;
        const bool valid = node < N;
        const int beg = valid ? rowptr[node] : 0;
        const int end = valid ? rowptr[node + 1] : 0;
        const int deg = end - beg;

        const int grp = (EPH == 1) ? 0 : (sl >> 4);
        const int c0  = (EPH == 1) ? sl * 8 : (sl & 15) * 8;
        const int sb  = c0 >> 6;
        const uint8_t* hb = hf + c0;

        float ad[HEADS];
        #pragma unroll
        for (int h = 0; h < HEADS; ++h) ad[h] = valid ? adst[node * HEADS + h] : 0.f;

        float acc8[8] = {};
        float psum = 0.f;

        auto fmau8 = [&](uint2 v, float q) {
            acc8[0] = fmaf(ub0(v.x), q, acc8[0]);
            acc8[1] = fmaf(ub1(v.x), q, acc8[1]);
            acc8[2] = fmaf(ub2(v.x), q, acc8[2]);
            acc8[3] = fmaf(ub3(v.x), q, acc8[3]);
            acc8[4] = fmaf(ub0(v.y), q, acc8[4]);
            acc8[5] = fmaf(ub1(v.y), q, acc8[5]);
            acc8[6] = fmaf(ub2(v.y), q, acc8[6]);
            acc8[7] = fmaf(ub3(v.y), q, acc8[7]);
        };

        // uniform 8-deep batched gather; cnt rounded up, padding q==0
        auto agg_chunk = [&](int cnt) {
            const int steps = (cnt + 8 * EPH - 1) / (8 * EPH);
            for (int s = 0; s < steps; ++s) {
                const int e = s * 8 * EPH;
                int o[8]; float q[8]; uint2 v[8];
                #pragma unroll
                for (int u = 0; u < 8; ++u) {
                    o[u] = soff[wid][half][e + u * EPH + grp];
                    q[u] = pal[wid][half][e + u * EPH + grp][sb];
                }
                #pragma unroll
                for (int u = 0; u < 8; ++u) v[u] = *(const uint2*)(hb + o[u]);
                #pragma unroll
                for (int u = 0; u < 8; ++u) { psum += q[u]; fmau8(v[u], q[u]); }
            }
        };

        if (deg <= 32) {
            const bool act = sl < deg;
            int msrc = act ? csrc[beg + sl] : 0;
            float lv[HEADS];
            if constexpr (HEADS == 4) {
                float4 a4 = ((const float4*)asrc)[msrc];
                lv[0] = a4.x; lv[1] = a4.y; lv[2] = a4.z; lv[3] = a4.w;
            } else {
                lv[0] = asrc[msrc];
            }
            float pe_[HEADS];
            #pragma unroll
            for (int h = 0; h < HEADS; ++h) {
                float v;
                if (act) { v = lv[h] + ad[h]; v = v > 0.f ? v : NEG_SLOPE * v; }
                else v = -INFINITY;
                float mx = v;
                #pragma unroll
                for (int o = 1; o < 32; o <<= 1) mx = fmaxf(mx, __shfl_xor(mx, o, 64));
                float pe = act ? __expf(v - mx) : 0.f;
                float ps = pe;
                #pragma unroll
                for (int o = 1; o < 32; o <<= 1) ps += __shfl_xor(ps, o, 64);
                pe_[h] = pe * (1.f / (ps + 1e-16f));
            }
            soff[wid][half][sl] = msrc * D;
            if constexpr (HEADS == 4) {
                float4 hs = act ? ((const float4*)hscale)[msrc]
                                : make_float4(0.f, 0.f, 0.f, 0.f);
                *(float4*)&pal[wid][half][sl][0] =
                    make_float4(pe_[0] * hs.x, pe_[1] * hs.y, pe_[2] * hs.z, pe_[3] * hs.w);
            } else {
                float2 hs = act ? ((const float2*)hscale)[msrc] : make_float2(0.f, 0.f);
                *(float2*)&pal[wid][half][sl][0] = make_float2(pe_[0] * hs.x, pe_[0] * hs.y);
            }
            asm volatile("s_waitcnt lgkmcnt(0)" ::: "memory");
            agg_chunk(deg);
        } else {
            float mx[HEADS], sm[HEADS], inv[HEADS];
            #pragma unroll
            for (int h = 0; h < HEADS; ++h) mx[h] = -INFINITY;
            for (int j = beg + sl; j < end; j += 32) {
                int s = csrc[j];
                #pragma unroll
                for (int h = 0; h < HEADS; ++h) {
                    float v = asrc[s * HEADS + h] + ad[h];
                    v = v > 0.f ? v : NEG_SLOPE * v;
                    mx[h] = fmaxf(mx[h], v);
                }
            }
            #pragma unroll
            for (int h = 0; h < HEADS; ++h) {
                #pragma unroll
                for (int o = 1; o < 32; o <<= 1) mx[h] = fmaxf(mx[h], __shfl_xor(mx[h], o, 64));
                sm[h] = 0.f;
            }
            for (int j = beg + sl; j < end; j += 32) {
                int s = csrc[j];
                #pragma unroll
                for (int h = 0; h < HEADS; ++h) {
                    float v = asrc[s * HEADS + h] + ad[h];
                    v = v > 0.f ? v : NEG_SLOPE * v;
                    sm[h] += __expf(v - mx[h]);
                }
            }
            #pragma unroll
            for (int h = 0; h < HEADS; ++h) {
                #pragma unroll
                for (int o = 1; o < 32; o <<= 1) sm[h] += __shfl_xor(sm[h], o, 64);
                inv[h] = 1.f / (sm[h] + 1e-16f);
            }
            for (int base2 = beg; base2 < end; base2 += 32) {
                int ne = min(32, end - base2);
                bool act2 = sl < ne;
                int msrc = csrc[base2 + (act2 ? sl : 0)];
                soff[wid][half][sl] = msrc * D;
                if constexpr (HEADS == 4) {
                    float4 hs = act2 ? ((const float4*)hscale)[msrc]
                                     : make_float4(0.f, 0.f, 0.f, 0.f);
                    float hsv[4] = {hs.x, hs.y, hs.z, hs.w};
                    #pragma unroll
                    for (int h = 0; h < 4; ++h) {
                        float pv = 0.f;
                        if (act2) {
                            float v = asrc[msrc * 4 + h] + ad[h];
                            v = v > 0.f ? v : NEG_SLOPE * v;
                            pv = __expf(v - mx[h]) * inv[h];
                        }
                        pal[wid][half][sl][h] = pv * hsv[h];
                    }
                } else {
                    float2 hs = act2 ? ((const float2*)hscale)[msrc] : make_float2(0.f, 0.f);
                    float pv = 0.f;
                    if (act2) {
                        float v = asrc[msrc] + ad[0];
                        v = v > 0.f ? v : NEG_SLOPE * v;
                        pv = __expf(v - mx[0]) * inv[0];
                    }
                    pal[wid][half][sl][0] = pv * hs.x;
                    pal[wid][half][sl][1] = pv * hs.y;
                }
                asm volatile("s_waitcnt lgkmcnt(0)" ::: "memory");
                agg_chunk(ne);
                asm volatile("s_waitcnt lgkmcnt(0)" ::: "memory");
            }
        }

        if constexpr (EPH == 2) {
            #pragma unroll
            for (int i = 0; i < 8; ++i)
                acc8[i] += __shfl_xor(acc8[i], 16, 64);
            psum += __shfl_xor(psum, 16, 64);
        }

        // ---- epilogue: excess-128 fix + folded BN + ReLU -> bf16 ----
        if (valid && (EPH == 1 || sl < 16)) {
            float4 Sa = *(const float4*)&bnS[c0];
            float4 Sb = *(const float4*)&bnS[c0 + 4];
            float4 Ta = *(const float4*)&bnT[c0];
            float4 Tb = *(const float4*)&bnT[c0 + 4];
            float S8[8] = {Sa.x, Sa.y, Sa.z, Sa.w, Sb.x, Sb.y, Sb.z, Sb.w};
            float T8[8] = {Ta.x, Ta.y, Ta.z, Ta.w, Tb.x, Tb.y, Tb.z, Tb.w};
            bf16x8 ov;
            #pragma unroll
            for (int i = 0; i < 8; ++i) {
                float v = fmaf(acc8[i] - 128.f * psum, S8[i], T8[i]);
                ov[i] = (__bf16)fmaxf(v, 0.f);
            }
            if constexpr (OUTP)
                *(bf16x8*)&out[((size_t)(c0 >> 3) * N + node) * 8] = ov;   // k-panel
            else
                *(bf16x8*)&out[(size_t)node * D + c0] = ov;                // row-major
        }
    }
}

// ---------- gate MLP via MFMA (x4 row-major) ----------
__global__ __launch_bounds__(256) void gate_gemm_kernel(
    const __bf16* __restrict__ x4, const __bf16* __restrict__ pw1t,
    const float* __restrict__ pb1, const float* __restrict__ pw2,
    const float* __restrict__ pb2, float* __restrict__ gate, int N) {
    const int w    = threadIdx.x >> 6;
    const int lane = threadIdx.x & 63;
    const int l16  = lane & 15, hi4 = lane >> 4;
    const int n0 = (blockIdx.x * 4 + w) * 16;
    if (n0 >= N) return;
    const int arow = min(n0 + l16, N - 1);
    f32x4 acc[2] = {};
    #pragma unroll
    for (int k0 = 0; k0 < 128; k0 += 32) {
        bf16x8 af = *(const bf16x8*)&x4[(size_t)arow * 128 + k0 + hi4 * 8];
        bf16x8 b0 = *(const bf16x8*)&pw1t[(size_t)l16 * 128 + k0 + hi4 * 8];
        bf16x8 b1 = *(const bf16x8*)&pw1t[(size_t)(16 + l16) * 128 + k0 + hi4 * 8];
        acc[0] = __builtin_amdgcn_mfma_f32_16x16x32_bf16(af, b0, acc[0], 0, 0, 0);
        acc[1] = __builtin_amdgcn_mfma_f32_16x16x32_bf16(af, b1, acc[1], 0, 0, 0);
    }
    float pb1a = pb1[l16], pb1b = pb1[16 + l16];
    float w2a = pw2[l16], w2b = pw2[16 + l16];
    #pragma unroll
    for (int q = 0; q < 4; ++q) {
        float g = fmaxf(acc[0][q] + pb1a, 0.f) * w2a +
                  fmaxf(acc[1][q] + pb1b, 0.f) * w2b;
        #pragma unroll
        for (int o = 1; o < 16; o <<= 1) g += __shfl_xor(g, o, 64);
        int row = n0 + hi4 * 4 + q;
        if (l16 == 0 && row < N) gate[row] = g + pb2[0];
    }
}

// ---------- block-per-graph pooling ----------
__global__ __launch_bounds__(128) void pool_kernel(
    const __bf16* __restrict__ x4, const float* __restrict__ gate,
    const int* __restrict__ gstart, float* __restrict__ out) {
    const int g = blockIdx.x;
    const int t = threadIdx.x;
    const int beg = gstart[g], end = gstart[g + 1];
    __shared__ float red[128];
    __shared__ float wbuf[128];
    float m = -INFINITY;
    for (int n = beg + t; n < end; n += 128) m = fmaxf(m, gate[n]);
    red[t] = m; __syncthreads();
    for (int off = 64; off > 0; off >>= 1) {
        if (t < off) red[t] = fmaxf(red[t], red[t + off]);
        __syncthreads();
    }
    m = red[0]; __syncthreads();
    float s = 0.f;
    for (int n = beg + t; n < end; n += 128) s += expf(gate[n] - m);
    red[t] = s; __syncthreads();
    for (int off = 64; off > 0; off >>= 1) {
        if (t < off) red[t] += red[t + off];
        __syncthreads();
    }
    const float inv = 1.f / (red[0] + 1e-16f);
    __syncthreads();
    float acc = 0.f;
    for (int base = beg; base < end; base += 128) {
        int ne = min(128, end - base);
        if (t < ne) wbuf[t] = expf(gate[base + t] - m) * inv;
        __syncthreads();
        for (int i = 0; i < ne; ++i)
            acc = fmaf(wbuf[i], (float)x4[(size_t)(base + i) * 128 + t], acc);
        __syncthreads();
    }
    out[(size_t)g * 160 + t] = acc;
}

// ---------- global-feature MLP ----------
__global__ void gfeat_kernel(const float* __restrict__ gfeat,
                             const float* __restrict__ gw, const float* __restrict__ gb,
                             float* __restrict__ out) {
    const int g = blockIdx.x;
    const int k = threadIdx.x;
    if (k < 32) {
        float t = gb[k];
        #pragma unroll
        for (int j = 0; j < 7; ++j) t = fmaf(gfeat[g * 7 + j], gw[j * 32 + k], t);
        out[(size_t)g * 160 + 128 + k] = fmaxf(t, 0.f);
    }
}

// ==========================================================================
extern "C" void kernel_launch(void* const* d_in, const int* in_sizes, int n_in,
                              void* d_out, int out_size, void* d_ws, size_t ws_size,
                              hipStream_t stream) {
    const float* x      = (const float*)d_in[0];
    const int*   ei     = (const int*)  d_in[1];
    const int*   batch  = (const int*)  d_in[2];
    const float* gfeat  = (const float*)d_in[3];

    const int N    = in_sizes[2];
    const int E    = in_sizes[1] / 2;
    const int G    = in_sizes[3] / 7;
    const int IN   = in_sizes[0] / N;
    const int Etot = E + N;

    const float* W[4];  const float* avs[4]; const float* avd[4]; const float* bi[4];
    const float* ga[4]; const float* be[4];  const float* mu[4];  const float* va[4];
    for (int l = 0; l < 4; ++l) {
        int o = 4 + 8 * l;
        W[l]   = (const float*)d_in[o + 0];
        avs[l] = (const float*)d_in[o + 1];
        avd[l] = (const float*)d_in[o + 2];
        bi[l]  = (const float*)d_in[o + 3];
        ga[l]  = (const float*)d_in[o + 4];
        be[l]  = (const float*)d_in[o + 5];
        mu[l]  = (const float*)d_in[o + 6];
        va[l]  = (const float*)d_in[o + 7];
    }
    const float* pw1 = (const float*)d_in[36];
    const float* pb1 = (const float*)d_in[37];
    const float* pw2 = (const float*)d_in[38];
    const float* pb2 = (const float*)d_in[39];
    const float* gw  = (const float*)d_in[40];
    const float* gb  = (const float*)d_in[41];

    float* out = (float*)d_out;

    float* ws = (float*)d_ws;
    __bf16* xb = (__bf16*)ws; ws += (size_t)N * 32;      // panels [8][N][8]
    uint8_t* h8 = (uint8_t*)ws; ws += (size_t)N * 64;
    float* hsc = ws;  ws += (size_t)N * 4;               // [N][NSB<=4]
    __bf16* x1 = (__bf16*)ws; ws += (size_t)N * 128;     // panels [32][N][8]
    __bf16* x2 = (__bf16*)ws; ws += (size_t)N * 128;
    __bf16* x3 = (__bf16*)ws; ws += (size_t)N * 128;
    __bf16* wt1 = (__bf16*)ws; ws += 256 * 64 / 2;       // panels [8][256][8]
    __bf16* wt2 = (__bf16*)ws; ws += 256 * 256 / 2;      // panels [32][256][8]
    __bf16* wt3 = (__bf16*)ws; ws += 256 * 256 / 2;
    __bf16* wt4 = (__bf16*)ws; ws += 128 * 256 / 2;      // panels [32][128][8]
    __bf16* pw1t = (__bf16*)ws; ws += 32 * 128 / 2;      // row-major [32][128]
    float* bnS = ws; ws += 4 * 256;
    float* bnT = ws; ws += 4 * 256;
    float* asrc = ws;  ws += (size_t)N * 4;
    float* adst = ws;  ws += (size_t)N * 4;
    float* gate = ws;  ws += N;
    int* deg    = (int*)ws; ws += N;
    int* cursor = (int*)ws; ws += N;
    int* rowptr = (int*)ws; ws += (N + 1);
    int* csrc   = (int*)ws; ws += Etot;
    int* gstart = (int*)ws; ws += (G + 1);
    int* bsum   = (int*)ws; ws += 256;
    int* bpref  = (int*)ws; ws += 256;
    __bf16* x4 = x1;

    const int SB = (N + SCB - 1) / SCB;

    hipLaunchKernelGGL(conv_pad_kernel, dim3(512), dim3(256), 0, stream, x, xb, N, IN);
    hipLaunchKernelGGL(prep_all_kernel, dim3(932), dim3(256), 0, stream,
                       W[0], W[1], W[2], W[3], pw1, wt1, wt2, wt3, wt4, pw1t,
                       bi[0], ga[0], be[0], mu[0], va[0],
                       bi[1], ga[1], be[1], mu[1], va[1],
                       bi[2], ga[2], be[2], mu[2], va[2],
                       bi[3], ga[3], be[3], mu[3], va[3],
                       bnS, bnT, IN);

    hipMemsetAsync(deg, 0, (size_t)N * 4, stream);
    hipLaunchKernelGGL(deg_count_kernel, dim3((Etot + 255) / 256), dim3(256), 0, stream,
                       ei, deg, E, Etot);
    hipLaunchKernelGGL(scan1_kernel, dim3(SB), dim3(256), 0, stream, deg, bsum, N);
    hipLaunchKernelGGL(scan2_kernel, dim3(1), dim3(256), 0, stream, bsum, bpref, SB,
                       &rowptr[N]);
    hipLaunchKernelGGL(scan3_kernel, dim3(SB), dim3(256), 0, stream, deg, bpref,
                       rowptr, cursor, N);
    hipLaunchKernelGGL(scatter_kernel, dim3((Etot + 255) / 256), dim3(256), 0, stream,
                       ei, cursor, csrc, E, Etot);
    hipLaunchKernelGGL(gstart_kernel, dim3((N + 255) / 256), dim3(256), 0, stream,
                       batch, gstart, N, G);

    const int grid32  = (N + 31) / 32;
    const int grid64  = (N + 63) / 64;
    const int gatgrid = 2048;

    hipLaunchKernelGGL((gemm_fused<256, 64, false>), dim3(grid32), dim3(256), 0, stream,
                       xb, nullptr, wt1, avs[0], avd[0], h8, hsc, asrc, adst, N);
    hipLaunchKernelGGL((gat_agg<4, 64, true>), dim3(gatgrid), dim3(256), 0, stream,
                       rowptr, csrc, h8, hsc, asrc, adst, bnS + 0, bnT + 0, x1, N);
    hipLaunchKernelGGL((gemm_fused<256, 256, false>), dim3(grid32), dim3(256), 0, stream,
                       x1, nullptr, wt2, avs[1], avd[1], h8, hsc, asrc, adst, N);
    hipLaunchKernelGGL((gat_agg<4, 64, true>), dim3(gatgrid), dim3(256), 0, stream,
                       rowptr, csrc, h8, hsc, asrc, adst, bnS + 256, bnT + 256, x2, N);
    hipLaunchKernelGGL((gemm_fused<256, 256, true>), dim3(grid32), dim3(256), 0, stream,
                       x1, x2, wt3, avs[2], avd[2], h8, hsc, asrc, adst, N);
    hipLaunchKernelGGL((gat_agg<4, 64, true>), dim3(gatgrid), dim3(256), 0, stream,
                       rowptr, csrc, h8, hsc, asrc, adst, bnS + 512, bnT + 512, x3, N);
    hipLaunchKernelGGL((gemm_fused<128, 256, false>), dim3(grid64), dim3(256), 0, stream,
                       x3, nullptr, wt4, avs[3], avd[3], h8, hsc, asrc, adst, N);
    hipLaunchKernelGGL((gat_agg<1, 128, false>), dim3(gatgrid), dim3(256), 0, stream,
                       rowptr, csrc, h8, hsc, asrc, adst, bnS + 768, bnT + 768, x4, N);

    hipLaunchKernelGGL(gate_gemm_kernel, dim3((N + 63) / 64), dim3(256), 0, stream,
                       x4, pw1t, pb1, pw2, pb2, gate, N);
    hipLaunchKernelGGL(pool_kernel, dim3(G), dim3(128), 0, stream, x4, gate, gstart, out);
    hipLaunchKernelGGL(gfeat_kernel, dim3(G), dim3(64), 0, stream, gfeat, gw, gb, out);
}

// Round 17
// 351.048 us; speedup vs baseline: 1.4109x; 1.1694x over previous
//
#include <hip/hip_runtime.h>
#include <cstdint>
#include <cstddef>

#define NEG_SLOPE 0.2f
#define BN_EPS 1e-5f

typedef __bf16 bf16x8 __attribute__((ext_vector_type(8)));
typedef float  f32x4  __attribute__((ext_vector_type(4)));

// single-instruction byte->float (v_cvt_f32_ubyteN)
__device__ __forceinline__ float ub0(unsigned u) { return (float)(u & 0xffu); }
__device__ __forceinline__ float ub1(unsigned u) { return (float)((u >> 8) & 0xffu); }
__device__ __forceinline__ float ub2(unsigned u) { return (float)((u >> 16) & 0xffu); }
__device__ __forceinline__ float ub3(unsigned u) { return (float)((u >> 24) & 0xffu); }

// ---------- prep: x fp32 [N][K] -> bf16 k-panels xb[k/8][N][8], Kpad=64 ----------
__global__ void conv_pad_kernel(const float* __restrict__ x, __bf16* __restrict__ xb,
                                int N, int K) {
    int i = blockIdx.x * blockDim.x + threadIdx.x;   // n*8 + panel
    int total = N * 8;
    for (; i < total; i += gridDim.x * blockDim.x) {
        int n = i >> 3, p = i & 7;
        bf16x8 v;
        #pragma unroll
        for (int j = 0; j < 8; ++j) {
            int k = p * 8 + j;
            v[j] = (k < K) ? (__bf16)x[(size_t)n * K + k] : (__bf16)0.f;
        }
        *(bf16x8*)&xb[((size_t)p * N + n) * 8] = v;
    }
}

// ---------- prep: weight k-panel transposes + BN fold, one launch ----------
__global__ void prep_all_kernel(
    const float* __restrict__ W1, const float* __restrict__ W2,
    const float* __restrict__ W3, const float* __restrict__ W4,
    const float* __restrict__ PW1,
    __bf16* __restrict__ wt1, __bf16* __restrict__ wt2,
    __bf16* __restrict__ wt3, __bf16* __restrict__ wt4,
    __bf16* __restrict__ pw1t,
    const float* b1, const float* g1, const float* e1, const float* m1, const float* v1,
    const float* b2, const float* g2, const float* e2, const float* m2, const float* v2,
    const float* b3, const float* g3, const float* e3, const float* m3, const float* v3,
    const float* b4, const float* g4, const float* e4, const float* m4, const float* v4,
    float* __restrict__ bnS, float* __restrict__ bnT,   // [4][256]
    int IN) {
    int b = blockIdx.x;
    if (b >= 928) {
        int l = b - 928;
        int Dl = (l == 3) ? 128 : 256;
        int t = threadIdx.x;
        if (t < Dl) {
            const float* bias; const float* ga; const float* be;
            const float* mu;   const float* va;
            if (l == 0)      { bias = b1; ga = g1; be = e1; mu = m1; va = v1; }
            else if (l == 1) { bias = b2; ga = g2; be = e2; mu = m2; va = v2; }
            else if (l == 2) { bias = b3; ga = g3; be = e3; mu = m3; va = v3; }
            else             { bias = b4; ga = g4; be = e4; mu = m4; va = v4; }
            float S = ga[t] * rsqrtf(va[t] + BN_EPS);
            bnS[l * 256 + t] = S;
            bnT[l * 256 + t] = (bias[t] - mu[t]) * S + be[t];
        }
        return;
    }
    const float* W; __bf16* WT; int K, D, Kpad, col; bool panel = true;
    if (b < 256)      { W = W1;  WT = wt1;  K = IN;  D = 256; Kpad = 64;  col = b; }
    else if (b < 512) { W = W2;  WT = wt2;  K = 256; D = 256; Kpad = 256; col = b - 256; }
    else if (b < 768) { W = W3;  WT = wt3;  K = 256; D = 256; Kpad = 256; col = b - 512; }
    else if (b < 896) { W = W4;  WT = wt4;  K = 256; D = 128; Kpad = 256; col = b - 768; }
    else              { W = PW1; WT = pw1t; K = 128; D = 32;  Kpad = 128; col = b - 896; panel = false; }
    for (int k = threadIdx.x; k < Kpad; k += blockDim.x) {
        float v = (k < K) ? W[(size_t)k * D + col] : 0.f;
        if (panel)
            WT[((size_t)(k >> 3) * D + col) * 8 + (k & 7)] = (__bf16)v;
        else
            WT[(size_t)col * Kpad + k] = (__bf16)v;
    }
}

// ============ MFMA GEMM (32x64/wave) on k-panel inputs + fused alpha + u8 H ====
template<int DCOLS, int KT, bool HAS_A2>
__global__ __launch_bounds__(256) void gemm_fused(
    const __bf16* __restrict__ A, const __bf16* __restrict__ A2,
    const __bf16* __restrict__ WT,
    const float* __restrict__ asv, const float* __restrict__ adv,
    uint8_t* __restrict__ H8, float* __restrict__ hscale,
    float* __restrict__ alpha_s, float* __restrict__ alpha_d,
    int M) {
    constexpr int NSB = DCOLS / 64;
    constexpr int RB  = (DCOLS == 256) ? 32 : 64;
    const int w    = threadIdx.x >> 6;
    const int lane = threadIdx.x & 63;
    const int l16  = lane & 15, hi4 = lane >> 4;
    const int rbase = (DCOLS == 256) ? 0 : (w >> 1) * 32;
    const int ct    = (DCOLS == 256) ? w : (w & 1);
    const int col0w = ct * 64;
    const int n0 = blockIdx.x * RB;

    f32x4 acc[2][4] = {};
    int arow[2];
    #pragma unroll
    for (int i = 0; i < 2; ++i) {
        int r = n0 + rbase + i * 16 + l16;
        arow[i] = (r < M) ? r : (M - 1);
    }

    #pragma unroll
    for (int k0 = 0; k0 < KT; k0 += 32) {
        const int panel = (k0 >> 3) + hi4;
        bf16x8 af[2], bfr[4];
        #pragma unroll
        for (int i = 0; i < 2; ++i) {
            bf16x8 v = *(const bf16x8*)&A[((size_t)panel * M + arow[i]) * 8];
            if (HAS_A2) {
                bf16x8 v2 = *(const bf16x8*)&A2[((size_t)panel * M + arow[i]) * 8];
                #pragma unroll
                for (int j = 0; j < 8; ++j) v[j] = (__bf16)((float)v[j] + (float)v2[j]);
            }
            af[i] = v;
        }
        #pragma unroll
        for (int j = 0; j < 4; ++j)
            bfr[j] = *(const bf16x8*)&WT[((size_t)panel * DCOLS + col0w + j * 16 + l16) * 8];
        #pragma unroll
        for (int i = 0; i < 2; ++i)
            #pragma unroll
            for (int j = 0; j < 4; ++j)
                acc[i][j] = __builtin_amdgcn_mfma_f32_16x16x32_bf16(
                    af[i], bfr[j], acc[i][j], 0, 0, 0);
    }

    // ---- fused alpha (partial dot over this wave's 64 cols) ----
    float asc[4], adc[4];
    #pragma unroll
    for (int j = 0; j < 4; ++j) {
        int c = col0w + j * 16 + l16;
        asc[j] = asv[c]; adc[j] = adv[c];
    }
    __shared__ float as_l[(DCOLS == 128) ? 64 : 1][2], ad_l[(DCOLS == 128) ? 64 : 1][2];
    #pragma unroll
    for (int i = 0; i < 2; ++i)
        #pragma unroll
        for (int q = 0; q < 4; ++q) {
            float ps = 0.f, pd = 0.f;
            #pragma unroll
            for (int j = 0; j < 4; ++j) {
                float v = acc[i][j][q];
                ps = fmaf(v, asc[j], ps);
                pd = fmaf(v, adc[j], pd);
            }
            #pragma unroll
            for (int o = 1; o < 16; o <<= 1) {
                ps += __shfl_xor(ps, o, 64);
                pd += __shfl_xor(pd, o, 64);
            }
            int rl = rbase + i * 16 + hi4 * 4 + q;
            if constexpr (DCOLS == 256) {
                int row = n0 + rl;
                if (l16 == 0 && row < M) {
                    alpha_s[row * 4 + w] = ps;
                    alpha_d[row * 4 + w] = pd;
                }
            } else {
                if (l16 == 0) { as_l[rl][ct] = ps; ad_l[rl][ct] = pd; }
            }
        }
    if constexpr (DCOLS == 128) {
        __syncthreads();
        int t = threadIdx.x;
        if (t < 64) {
            int row = n0 + t;
            if (row < M) {
                alpha_s[row] = as_l[t][0] + as_l[t][1];
                alpha_d[row] = ad_l[t][0] + ad_l[t][1];
            }
        }
    }

    // ---- per-wave (row, 64-col block) max|acc| -> quantize (excess-128) ----
    #pragma unroll
    for (int i = 0; i < 2; ++i)
        #pragma unroll
        for (int q = 0; q < 4; ++q) {
            float m = fabsf(acc[i][0][q]);
            #pragma unroll
            for (int j = 1; j < 4; ++j) m = fmaxf(m, fabsf(acc[i][j][q]));
            #pragma unroll
            for (int o = 1; o < 16; o <<= 1) m = fmaxf(m, __shfl_xor(m, o, 64));
            float qinv = (m > 1e-30f) ? 127.f / m : 0.f;
            int row = n0 + rbase + i * 16 + hi4 * 4 + q;
            if (row < M) {
                if (l16 == 0) hscale[row * NSB + ct] = m * (1.f / 127.f);
                #pragma unroll
                for (int j = 0; j < 4; ++j)
                    H8[(size_t)row * DCOLS + col0w + j * 16 + l16] =
                        (uint8_t)((int)rintf(acc[i][j][q] * qinv) + 128);
            }
        }
}

// ================= CSR build via bucketed counting sort =================
#define NPB_SHIFT 7           // 128 nodes per bucket
#define NPB 128
#define NBMAX 512
#define P3CH 4096
#define STAGE 4608

// P1: per-bucket histogram (LDS-aggregated)
__global__ __launch_bounds__(256) void bcount_kernel(const int* __restrict__ ei,
                                                     int* __restrict__ bcnt,
                                                     int E, int Etot) {
    __shared__ int bc[NBMAX];
    for (int i = threadIdx.x; i < NBMAX; i += 256) bc[i] = 0;
    __syncthreads();
    for (int e = blockIdx.x * blockDim.x + threadIdx.x; e < Etot;
         e += gridDim.x * blockDim.x) {
        int d = (e < E) ? ei[E + e] : e - E;
        atomicAdd(&bc[d >> NPB_SHIFT], 1);
    }
    __syncthreads();
    for (int i = threadIdx.x; i < NBMAX; i += 256)
        if (bc[i]) atomicAdd(&bcnt[i], bc[i]);
}

// P2: scan bucket counts -> bbase, bcursor; rowptr[N] = Etot
__global__ __launch_bounds__(512) void bscan_kernel(const int* __restrict__ bcnt,
                                                    int* __restrict__ bbase,
                                                    int* __restrict__ bcursor,
                                                    int* __restrict__ rowptrN, int Etot) {
    __shared__ int sm[512];
    const int t = threadIdx.x;
    int v = bcnt[t];
    sm[t] = v;
    __syncthreads();
    for (int off = 1; off < 512; off <<= 1) {
        int u = (t >= off) ? sm[t - off] : 0;
        __syncthreads();
        sm[t] += u;
        __syncthreads();
    }
    bbase[t] = sm[t] - v;
    bcursor[t] = sm[t] - v;
    if (t == 0) *rowptrN = Etot;
}

// P3: partition edges into bucket regions (chunk-local reservation)
__global__ __launch_bounds__(256) void partition_kernel(const int* __restrict__ ei,
                                                        int* __restrict__ bcursor,
                                                        int2* __restrict__ tmp,
                                                        int E, int Etot) {
    __shared__ int lcnt[NBMAX], gb[NBMAX], lcur[NBMAX];
    const int t = threadIdx.x;
    const int base = blockIdx.x * P3CH;
    for (int i = t; i < NBMAX; i += 256) { lcnt[i] = 0; lcur[i] = 0; }
    __syncthreads();
    for (int i = t; i < P3CH; i += 256) {
        int e = base + i;
        if (e < Etot) {
            int d = (e < E) ? ei[E + e] : e - E;
            atomicAdd(&lcnt[d >> NPB_SHIFT], 1);
        }
    }
    __syncthreads();
    for (int i = t; i < NBMAX; i += 256)
        if (lcnt[i] > 0) gb[i] = atomicAdd(&bcursor[i], lcnt[i]);
    __syncthreads();
    for (int i = t; i < P3CH; i += 256) {
        int e = base + i;
        if (e < Etot) {
            int s, d;
            if (e < E) { s = ei[e]; d = ei[E + e]; } else { s = d = e - E; }
            int b = d >> NPB_SHIFT;
            int pos = gb[b] + atomicAdd(&lcur[b], 1);
            tmp[pos] = make_int2(s, d);
        }
    }
}

// P4: per-bucket local sort -> rowptr + csrc (coalesced LDS-staged writes)
__global__ __launch_bounds__(256) void bucket_build_kernel(
    const int2* __restrict__ tmp, const int* __restrict__ bbase,
    const int* __restrict__ bcnt,
    int* __restrict__ rowptr, int* __restrict__ csrc, int N) {
    __shared__ int ncnt[NPB];
    __shared__ int nst[NPB];
    __shared__ int stage[STAGE];
    const int b = blockIdx.x;
    const int t = threadIdx.x;
    const int node0 = b << NPB_SHIFT;
    const int nn = min(NPB, N - node0);
    const int pbase = bbase[b];
    const int cnt = bcnt[b];
    const bool fits = (cnt <= STAGE);
    for (int i = t; i < NPB; i += 256) ncnt[i] = 0;
    __syncthreads();
    for (int i = t; i < cnt; i += 256) {
        int2 p = tmp[pbase + i];
        atomicAdd(&ncnt[p.y - node0], 1);
    }
    __syncthreads();
    if (t < NPB) nst[t] = ncnt[t];
    __syncthreads();
    for (int off = 1; off < NPB; off <<= 1) {
        int u = (t < NPB && t >= off) ? nst[t - off] : 0;
        __syncthreads();
        if (t < NPB) nst[t] += u;
        __syncthreads();
    }
    if (t < nn) rowptr[node0 + t] = pbase + nst[t] - ncnt[t];
    __syncthreads();
    if (t < NPB) ncnt[t] = nst[t] - ncnt[t];   // reuse as cursors
    __syncthreads();
    for (int i = t; i < cnt; i += 256) {
        int2 p = tmp[pbase + i];
        int lpos = atomicAdd(&ncnt[p.y - node0], 1);
        if (fits) stage[lpos] = p.x;
        else      csrc[pbase + lpos] = p.x;
    }
    __syncthreads();
    if (fits)
        for (int i = t; i < cnt; i += 256)
            csrc[pbase + i] = stage[i];
}

__global__ void gstart_kernel(const int* __restrict__ batch, int* __restrict__ gstart,
                              int N, int G) {
    int n = blockIdx.x * blockDim.x + threadIdx.x;
    if (n >= N) return;
    int b = batch[n];
    if (n == 0) { for (int g = 0; g <= b; ++g) gstart[g] = 0; }
    else {
        int bp = batch[n - 1];
        for (int g = bp + 1; g <= b; ++g) gstart[g] = n;
    }
    if (n == N - 1) { for (int g = b + 1; g <= G; ++g) gstart[g] = N; }
}

// ============ GAT edge phase: TWO nodes per wave, 8-deep batched u8 gather ====
template<int HEADS, int C, bool OUTP>
__global__ __launch_bounds__(256) void gat_agg(
    const int* __restrict__ rowptr, const int* __restrict__ csrc,
    const uint8_t* __restrict__ hf, const float* __restrict__ hscale,
    const float* __restrict__ asrc, const float* __restrict__ adst,
    const float* __restrict__ bnS, const float* __restrict__ bnT,
    __bf16* __restrict__ out, int N) {
    constexpr int D   = HEADS * C;
    constexpr int NSB = D / 64;
    constexpr int LPE = D / 8;
    constexpr int EPH = 32 / LPE;

    const int wid  = threadIdx.x >> 6;
    const int lane = threadIdx.x & 63;
    const int half = lane >> 5;
    const int sl   = lane & 31;

    __shared__ int   soff[4][2][32];
    __shared__ float pal[4][2][32][NSB];

    const int npairs = (N + 1) >> 1;

    for (int pair = blockIdx.x * 4 + wid; pair < npairs; pair += gridDim.x * 4) {
        const int node = pair * 2 + half;
        const bool valid = node < N;
        const int beg = valid ? rowptr[node] : 0;
        const int end = valid ? rowptr[node + 1] : 0;
        const int deg = end - beg;

        const int grp = (EPH == 1) ? 0 : (sl >> 4);
        const int c0  = (EPH == 1) ? sl * 8 : (sl & 15) * 8;
        const int sb  = c0 >> 6;
        const uint8_t* hb = hf + c0;

        float ad[HEADS];
        #pragma unroll
        for (int h = 0; h < HEADS; ++h) ad[h] = valid ? adst[node * HEADS + h] : 0.f;

        float acc8[8] = {};
        float psum = 0.f;

        auto fmau8 = [&](uint2 v, float q) {
            acc8[0] = fmaf(ub0(v.x), q, acc8[0]);
            acc8[1] = fmaf(ub1(v.x), q, acc8[1]);
            acc8[2] = fmaf(ub2(v.x), q, acc8[2]);
            acc8[3] = fmaf(ub3(v.x), q, acc8[3]);
            acc8[4] = fmaf(ub0(v.y), q, acc8[4]);
            acc8[5] = fmaf(ub1(v.y), q, acc8[5]);
            acc8[6] = fmaf(ub2(v.y), q, acc8[6]);
            acc8[7] = fmaf(ub3(v.y), q, acc8[7]);
        };

        auto agg_chunk = [&](int cnt) {
            const int steps = (cnt + 8 * EPH - 1) / (8 * EPH);
            for (int s = 0; s < steps; ++s) {
                const int e = s * 8 * EPH;
                int o[8]; float q[8]; uint2 v[8];
                #pragma unroll
                for (int u = 0; u < 8; ++u) {
                    o[u] = soff[wid][half][e + u * EPH + grp];
                    q[u] = pal[wid][half][e + u * EPH + grp][sb];
                }
                #pragma unroll
                for (int u = 0; u < 8; ++u) v[u] = *(const uint2*)(hb + o[u]);
                #pragma unroll
                for (int u = 0; u < 8; ++u) { psum += q[u]; fmau8(v[u], q[u]); }
            }
        };

        if (deg <= 32) {
            const bool act = sl < deg;
            int msrc = act ? csrc[beg + sl] : 0;
            float lv[HEADS];
            if constexpr (HEADS == 4) {
                float4 a4 = ((const float4*)asrc)[msrc];
                lv[0] = a4.x; lv[1] = a4.y; lv[2] = a4.z; lv[3] = a4.w;
            } else {
                lv[0] = asrc[msrc];
            }
            float pe_[HEADS];
            #pragma unroll
            for (int h = 0; h < HEADS; ++h) {
                float v;
                if (act) { v = lv[h] + ad[h]; v = v > 0.f ? v : NEG_SLOPE * v; }
                else v = -INFINITY;
                float mx = v;
                #pragma unroll
                for (int o = 1; o < 32; o <<= 1) mx = fmaxf(mx, __shfl_xor(mx, o, 64));
                float pe = act ? __expf(v - mx) : 0.f;
                float ps = pe;
                #pragma unroll
                for (int o = 1; o < 32; o <<= 1) ps += __shfl_xor(ps, o, 64);
                pe_[h] = pe * (1.f / (ps + 1e-16f));
            }
            soff[wid][half][sl] = msrc * D;
            if constexpr (HEADS == 4) {
                float4 hs = act ? ((const float4*)hscale)[msrc]
                                : make_float4(0.f, 0.f, 0.f, 0.f);
                *(float4*)&pal[wid][half][sl][0] =
                    make_float4(pe_[0] * hs.x, pe_[1] * hs.y, pe_[2] * hs.z, pe_[3] * hs.w);
            } else {
                float2 hs = act ? ((const float2*)hscale)[msrc] : make_float2(0.f, 0.f);
                *(float2*)&pal[wid][half][sl][0] = make_float2(pe_[0] * hs.x, pe_[0] * hs.y);
            }
            asm volatile("s_waitcnt lgkmcnt(0)" ::: "memory");
            agg_chunk(deg);
        } else {
            float mx[HEADS], sm[HEADS], inv[HEADS];
            #pragma unroll
            for (int h = 0; h < HEADS; ++h) mx[h] = -INFINITY;
            for (int j = beg + sl; j < end; j += 32) {
                int s = csrc[j];
                #pragma unroll
                for (int h = 0; h < HEADS; ++h) {
                    float v = asrc[s * HEADS + h] + ad[h];
                    v = v > 0.f ? v : NEG_SLOPE * v;
                    mx[h] = fmaxf(mx[h], v);
                }
            }
            #pragma unroll
            for (int h = 0; h < HEADS; ++h) {
                #pragma unroll
                for (int o = 1; o < 32; o <<= 1) mx[h] = fmaxf(mx[h], __shfl_xor(mx[h], o, 64));
                sm[h] = 0.f;
            }
            for (int j = beg + sl; j < end; j += 32) {
                int s = csrc[j];
                #pragma unroll
                for (int h = 0; h < HEADS; ++h) {
                    float v = asrc[s * HEADS + h] + ad[h];
                    v = v > 0.f ? v : NEG_SLOPE * v;
                    sm[h] += __expf(v - mx[h]);
                }
            }
            #pragma unroll
            for (int h = 0; h < HEADS; ++h) {
                #pragma unroll
                for (int o = 1; o < 32; o <<= 1) sm[h] += __shfl_xor(sm[h], o, 64);
                inv[h] = 1.f / (sm[h] + 1e-16f);
            }
            for (int base2 = beg; base2 < end; base2 += 32) {
                int ne = min(32, end - base2);
                bool act2 = sl < ne;
                int msrc = csrc[base2 + (act2 ? sl : 0)];
                soff[wid][half][sl] = msrc * D;
                if constexpr (HEADS == 4) {
                    float4 hs = act2 ? ((const float4*)hscale)[msrc]
                                     : make_float4(0.f, 0.f, 0.f, 0.f);
                    float hsv[4] = {hs.x, hs.y, hs.z, hs.w};
                    #pragma unroll
                    for (int h = 0; h < 4; ++h) {
                        float pv = 0.f;
                        if (act2) {
                            float v = asrc[msrc * 4 + h] + ad[h];
                            v = v > 0.f ? v : NEG_SLOPE * v;
                            pv = __expf(v - mx[h]) * inv[h];
                        }
                        pal[wid][half][sl][h] = pv * hsv[h];
                    }
                } else {
                    float2 hs = act2 ? ((const float2*)hscale)[msrc] : make_float2(0.f, 0.f);
                    float pv = 0.f;
                    if (act2) {
                        float v = asrc[msrc] + ad[0];
                        v = v > 0.f ? v : NEG_SLOPE * v;
                        pv = __expf(v - mx[0]) * inv[0];
                    }
                    pal[wid][half][sl][0] = pv * hs.x;
                    pal[wid][half][sl][1] = pv * hs.y;
                }
                asm volatile("s_waitcnt lgkmcnt(0)" ::: "memory");
                agg_chunk(ne);
                asm volatile("s_waitcnt lgkmcnt(0)" ::: "memory");
            }
        }

        if constexpr (EPH == 2) {
            #pragma unroll
            for (int i = 0; i < 8; ++i)
                acc8[i] += __shfl_xor(acc8[i], 16, 64);
            psum += __shfl_xor(psum, 16, 64);
        }

        // ---- epilogue: excess-128 fix + folded BN + ReLU -> bf16 ----
        if (valid && (EPH == 1 || sl < 16)) {
            float4 Sa = *(const float4*)&bnS[c0];
            float4 Sb = *(const float4*)&bnS[c0 + 4];
            float4 Ta = *(const float4*)&bnT[c0];
            float4 Tb = *(const float4*)&bnT[c0 + 4];
            float S8[8] = {Sa.x, Sa.y, Sa.z, Sa.w, Sb.x, Sb.y, Sb.z, Sb.w};
            float T8[8] = {Ta.x, Ta.y, Ta.z, Ta.w, Tb.x, Tb.y, Tb.z, Tb.w};
            bf16x8 ov;
            #pragma unroll
            for (int i = 0; i < 8; ++i) {
                float v = fmaf(acc8[i] - 128.f * psum, S8[i], T8[i]);
                ov[i] = (__bf16)fmaxf(v, 0.f);
            }
            if constexpr (OUTP)
                *(bf16x8*)&out[((size_t)(c0 >> 3) * N + node) * 8] = ov;   // k-panel
            else
                *(bf16x8*)&out[(size_t)node * D + c0] = ov;                // row-major
        }
    }
}

// ---------- gate MLP via MFMA (x4 row-major) ----------
__global__ __launch_bounds__(256) void gate_gemm_kernel(
    const __bf16* __restrict__ x4, const __bf16* __restrict__ pw1t,
    const float* __restrict__ pb1, const float* __restrict__ pw2,
    const float* __restrict__ pb2, float* __restrict__ gate, int N) {
    const int w    = threadIdx.x >> 6;
    const int lane = threadIdx.x & 63;
    const int l16  = lane & 15, hi4 = lane >> 4;
    const int n0 = (blockIdx.x * 4 + w) * 16;
    if (n0 >= N) return;
    const int arow = min(n0 + l16, N - 1);
    f32x4 acc[2] = {};
    #pragma unroll
    for (int k0 = 0; k0 < 128; k0 += 32) {
        bf16x8 af = *(const bf16x8*)&x4[(size_t)arow * 128 + k0 + hi4 * 8];
        bf16x8 b0 = *(const bf16x8*)&pw1t[(size_t)l16 * 128 + k0 + hi4 * 8];
        bf16x8 b1 = *(const bf16x8*)&pw1t[(size_t)(16 + l16) * 128 + k0 + hi4 * 8];
        acc[0] = __builtin_amdgcn_mfma_f32_16x16x32_bf16(af, b0, acc[0], 0, 0, 0);
        acc[1] = __builtin_amdgcn_mfma_f32_16x16x32_bf16(af, b1, acc[1], 0, 0, 0);
    }
    float pb1a = pb1[l16], pb1b = pb1[16 + l16];
    float w2a = pw2[l16], w2b = pw2[16 + l16];
    #pragma unroll
    for (int q = 0; q < 4; ++q) {
        float g = fmaxf(acc[0][q] + pb1a, 0.f) * w2a +
                  fmaxf(acc[1][q] + pb1b, 0.f) * w2b;
        #pragma unroll
        for (int o = 1; o < 16; o <<= 1) g += __shfl_xor(g, o, 64);
        int row = n0 + hi4 * 4 + q;
        if (l16 == 0 && row < N) gate[row] = g + pb2[0];
    }
}

// ---------- block-per-graph pooling ----------
__global__ __launch_bounds__(128) void pool_kernel(
    const __bf16* __restrict__ x4, const float* __restrict__ gate,
    const int* __restrict__ gstart, float* __restrict__ out) {
    const int g = blockIdx.x;
    const int t = threadIdx.x;
    const int beg = gstart[g], end = gstart[g + 1];
    __shared__ float red[128];
    __shared__ float wbuf[128];
    float m = -INFINITY;
    for (int n = beg + t; n < end; n += 128) m = fmaxf(m, gate[n]);
    red[t] = m; __syncthreads();
    for (int off = 64; off > 0; off >>= 1) {
        if (t < off) red[t] = fmaxf(red[t], red[t + off]);
        __syncthreads();
    }
    m = red[0]; __syncthreads();
    float s = 0.f;
    for (int n = beg + t; n < end; n += 128) s += expf(gate[n] - m);
    red[t] = s; __syncthreads();
    for (int off = 64; off > 0; off >>= 1) {
        if (t < off) red[t] += red[t + off];
        __syncthreads();
    }
    const float inv = 1.f / (red[0] + 1e-16f);
    __syncthreads();
    float acc = 0.f;
    for (int base = beg; base < end; base += 128) {
        int ne = min(128, end - base);
        if (t < ne) wbuf[t] = expf(gate[base + t] - m) * inv;
        __syncthreads();
        for (int i = 0; i < ne; ++i)
            acc = fmaf(wbuf[i], (float)x4[(size_t)(base + i) * 128 + t], acc);
        __syncthreads();
    }
    out[(size_t)g * 160 + t] = acc;
}

// ---------- global-feature MLP ----------
__global__ void gfeat_kernel(const float* __restrict__ gfeat,
                             const float* __restrict__ gw, const float* __restrict__ gb,
                             float* __restrict__ out) {
    const int g = blockIdx.x;
    const int k = threadIdx.x;
    if (k < 32) {
        float t = gb[k];
        #pragma unroll
        for (int j = 0; j < 7; ++j) t = fmaf(gfeat[g * 7 + j], gw[j * 32 + k], t);
        out[(size_t)g * 160 + 128 + k] = fmaxf(t, 0.f);
    }
}

// ==========================================================================
extern "C" void kernel_launch(void* const* d_in, const int* in_sizes, int n_in,
                              void* d_out, int out_size, void* d_ws, size_t ws_size,
                              hipStream_t stream) {
    const float* x      = (const float*)d_in[0];
    const int*   ei     = (const int*)  d_in[1];
    const int*   batch  = (const int*)  d_in[2];
    const float* gfeat  = (const float*)d_in[3];

    const int N    = in_sizes[2];
    const int E    = in_sizes[1] / 2;
    const int G    = in_sizes[3] / 7;
    const int IN   = in_sizes[0] / N;
    const int Etot = E + N;

    const float* W[4];  const float* avs[4]; const float* avd[4]; const float* bi[4];
    const float* ga[4]; const float* be[4];  const float* mu[4];  const float* va[4];
    for (int l = 0; l < 4; ++l) {
        int o = 4 + 8 * l;
        W[l]   = (const float*)d_in[o + 0];
        avs[l] = (const float*)d_in[o + 1];
        avd[l] = (const float*)d_in[o + 2];
        bi[l]  = (const float*)d_in[o + 3];
        ga[l]  = (const float*)d_in[o + 4];
        be[l]  = (const float*)d_in[o + 5];
        mu[l]  = (const float*)d_in[o + 6];
        va[l]  = (const float*)d_in[o + 7];
    }
    const float* pw1 = (const float*)d_in[36];
    const float* pb1 = (const float*)d_in[37];
    const float* pw2 = (const float*)d_in[38];
    const float* pb2 = (const float*)d_in[39];
    const float* gw  = (const float*)d_in[40];
    const float* gb  = (const float*)d_in[41];

    float* out = (float*)d_out;

    float* ws = (float*)d_ws;
    __bf16* xb = (__bf16*)ws; ws += (size_t)N * 32;      // panels [8][N][8]
    uint8_t* h8 = (uint8_t*)ws; ws += (size_t)N * 64;
    float* hsc = ws;  ws += (size_t)N * 4;               // [N][NSB<=4]
    __bf16* x1 = (__bf16*)ws; ws += (size_t)N * 128;     // panels [32][N][8]
    __bf16* x2 = (__bf16*)ws; ws += (size_t)N * 128;
    __bf16* x3 = (__bf16*)ws; ws += (size_t)N * 128;
    __bf16* wt1 = (__bf16*)ws; ws += 256 * 64 / 2;
    __bf16* wt2 = (__bf16*)ws; ws += 256 * 256 / 2;
    __bf16* wt3 = (__bf16*)ws; ws += 256 * 256 / 2;
    __bf16* wt4 = (__bf16*)ws; ws += 128 * 256 / 2;
    __bf16* pw1t = (__bf16*)ws; ws += 32 * 128 / 2;
    float* bnS = ws; ws += 4 * 256;
    float* bnT = ws; ws += 4 * 256;
    float* asrc = ws;  ws += (size_t)N * 4;
    float* adst = ws;  ws += (size_t)N * 4;
    float* gate = ws;  ws += N;
    int* rowptr = (int*)ws; ws += (N + 1);
    int* csrc   = (int*)ws; ws += Etot;
    int* gstart = (int*)ws; ws += (G + 1);
    int* bcnt   = (int*)ws; ws += NBMAX;
    int* bbase  = (int*)ws; ws += NBMAX;
    int* bcursor= (int*)ws; ws += NBMAX;
    ws = (float*)(((uintptr_t)ws + 15) & ~(uintptr_t)15);
    int2* tmp   = (int2*)ws; ws += (size_t)Etot * 2;
    __bf16* x4 = x1;

    const int NB = (N + NPB - 1) / NPB;

    hipLaunchKernelGGL(conv_pad_kernel, dim3(512), dim3(256), 0, stream, x, xb, N, IN);
    hipLaunchKernelGGL(prep_all_kernel, dim3(932), dim3(256), 0, stream,
                       W[0], W[1], W[2], W[3], pw1, wt1, wt2, wt3, wt4, pw1t,
                       bi[0], ga[0], be[0], mu[0], va[0],
                       bi[1], ga[1], be[1], mu[1], va[1],
                       bi[2], ga[2], be[2], mu[2], va[2],
                       bi[3], ga[3], be[3], mu[3], va[3],
                       bnS, bnT, IN);

    // ---- CSR build: bucketed counting sort ----
    hipMemsetAsync(bcnt, 0, NBMAX * sizeof(int), stream);
    hipLaunchKernelGGL(bcount_kernel, dim3(256), dim3(256), 0, stream, ei, bcnt, E, Etot);
    hipLaunchKernelGGL(bscan_kernel, dim3(1), dim3(512), 0, stream,
                       bcnt, bbase, bcursor, &rowptr[N], Etot);
    hipLaunchKernelGGL(partition_kernel, dim3((Etot + P3CH - 1) / P3CH), dim3(256), 0,
                       stream, ei, bcursor, tmp, E, Etot);
    hipLaunchKernelGGL(bucket_build_kernel, dim3(NB), dim3(256), 0, stream,
                       tmp, bbase, bcnt, rowptr, csrc, N);
    hipLaunchKernelGGL(gstart_kernel, dim3((N + 255) / 256), dim3(256), 0, stream,
                       batch, gstart, N, G);

    const int grid32  = (N + 31) / 32;
    const int grid64  = (N + 63) / 64;
    const int gatgrid = 2048;

    hipLaunchKernelGGL((gemm_fused<256, 64, false>), dim3(grid32), dim3(256), 0, stream,
                       xb, nullptr, wt1, avs[0], avd[0], h8, hsc, asrc, adst, N);
    hipLaunchKernelGGL((gat_agg<4, 64, true>), dim3(gatgrid), dim3(256), 0, stream,
                       rowptr, csrc, h8, hsc, asrc, adst, bnS + 0, bnT + 0, x1, N);
    hipLaunchKernelGGL((gemm_fused<256, 256, false>), dim3(grid32), dim3(256), 0, stream,
                       x1, nullptr, wt2, avs[1], avd[1], h8, hsc, asrc, adst, N);
    hipLaunchKernelGGL((gat_agg<4, 64, true>), dim3(gatgrid), dim3(256), 0, stream,
                       rowptr, csrc, h8, hsc, asrc, adst, bnS + 256, bnT + 256, x2, N);
    hipLaunchKernelGGL((gemm_fused<256, 256, true>), dim3(grid32), dim3(256), 0, stream,
                       x1, x2, wt3, avs[2], avd[2], h8, hsc, asrc, adst, N);
    hipLaunchKernelGGL((gat_agg<4, 64, true>), dim3(gatgrid), dim3(256), 0, stream,
                       rowptr, csrc, h8, hsc, asrc, adst, bnS + 512, bnT + 512, x3, N);
    hipLaunchKernelGGL((gemm_fused<128, 256, false>), dim3(grid64), dim3(256), 0, stream,
                       x3, nullptr, wt4, avs[3], avd[3], h8, hsc, asrc, adst, N);
    hipLaunchKernelGGL((gat_agg<1, 128, false>), dim3(gatgrid), dim3(256), 0, stream,
                       rowptr, csrc, h8, hsc, asrc, adst, bnS + 768, bnT + 768, x4, N);

    hipLaunchKernelGGL(gate_gemm_kernel, dim3((N + 63) / 64), dim3(256), 0, stream,
                       x4, pw1t, pb1, pw2, pb2, gate, N);
    hipLaunchKernelGGL(pool_kernel, dim3(G), dim3(128), 0, stream, x4, gate, gstart, out);
    hipLaunchKernelGGL(gfeat_kernel, dim3(G), dim3(64), 0, stream, gfeat, gw, gb, out);
}